// Round 4
// baseline (1516.939 us; speedup 1.0000x reference)
//
#include <hip/hip_runtime.h>
#include <cstdint>
#include <cstddef>

typedef _Float16 f16;
typedef _Float16 f16x8 __attribute__((ext_vector_type(8)));
typedef _Float16 f16x4 __attribute__((ext_vector_type(4)));
typedef float    f32x4 __attribute__((ext_vector_type(4)));

#define MFMA16(a,b,c) __builtin_amdgcn_mfma_f32_16x16x32_f16((a),(b),(c),0,0,0)

__device__ __forceinline__ float lrelu(float v){ return v >= 0.f ? v : 0.2f*v; }

// async global->LDS 16B copy; global addr per-lane, LDS dest = wave base + lane*16
__device__ __forceinline__ void async_copy16(const f16* g, f16* l){
  __builtin_amdgcn_global_load_lds(
      (const __attribute__((address_space(1))) void*)(uintptr_t)(const void*)g,
      (__attribute__((address_space(3))) void*)(uint32_t)(uintptr_t)(void*)l,
      16, 0, 0);
}

// ======================= prep kernels =======================

__global__ __launch_bounds__(256) void k_prep1x1(
    const float* __restrict__ wq, const float* __restrict__ wk, const float* __restrict__ wv,
    f16* __restrict__ oq, f16* __restrict__ ok, f16* __restrict__ ov)
{
  int i = blockIdx.x*256 + threadIdx.x;
  int sel = i >> 16, r = i & 65535;
  const float* s = sel==0 ? wq : (sel==1 ? wk : wv);
  f16* d = sel==0 ? oq : (sel==1 ? ok : ov);
  d[r] = (f16)s[r];
}

// 3x3 conv weights (co,ci,3,3) fp32 -> fp16 layout [tap][co][ci]
__global__ __launch_bounds__(256) void k_prep3x3(
    const float* __restrict__ w0, const float* __restrict__ w1, const float* __restrict__ w2,
    f16* __restrict__ o0, f16* __restrict__ o1, f16* __restrict__ o2)
{
  int i = blockIdx.x*256 + threadIdx.x;
  int sel = i / 589824;
  int r = i - sel*589824;
  int t = r >> 16; int rr = r & 65535; int co = rr >> 8; int ci = rr & 255;
  const float* s = sel==0 ? w0 : (sel==1 ? w1 : w2);
  f16* d = sel==0 ? o0 : (sel==1 ? o1 : o2);
  d[r] = (f16)s[(co*256 + ci)*9 + t];
}

__global__ __launch_bounds__(256) void k_pmask(const float* __restrict__ mask, float* __restrict__ pm,
                                               float* __restrict__ zp)
{
  int t = blockIdx.x*256 + threadIdx.x;
  if (t < 16) zp[t] = 0.f;               // zero page for conv3 halo DMA
  int b = t >> 8, n = t & 255;
  int y0 = (n>>4)<<2, x0 = (n&15)<<2;
  const float* mb = mask + b*4096;
  float s = 0.f;
  #pragma unroll
  for (int i=0;i<4;++i)
    #pragma unroll
    for (int j=0;j<4;++j) s += mb[(y0+i)*64 + x0+j];
  pm[t] = (s*(1.f/16.f) < 0.5f) ? 1.f : 0.f;
}

// ======================= NCHW f32 -> NHWC f16 (optional IN+lrelu) ===========
__global__ __launch_bounds__(256) void k_nchw2nhwc(
    const float* __restrict__ src, const float2* __restrict__ st, f16* __restrict__ dst)
{
  int idx = blockIdx.x;
  int y = idx & 63, b = idx >> 6;
  int tid = threadIdx.x;
  __shared__ f16 T[64*264];

  {
    const float* row = src + (size_t)(b*256+tid)*4096 + y*64;
    float mu = 0.f, ri = 1.f;
    bool doin = (st != nullptr);
    if (doin){ float2 s = st[b*256+tid]; mu = s.x; ri = s.y; }
    #pragma unroll
    for (int j=0;j<16;++j){
      float4 u = *(const float4*)(row + j*4);
      int x = j*4;
      float a0=(u.x-mu)*ri, a1=(u.y-mu)*ri, a2=(u.z-mu)*ri, a3=(u.w-mu)*ri;
      if (doin){ a0=lrelu(a0); a1=lrelu(a1); a2=lrelu(a2); a3=lrelu(a3); }
      T[(x+0)*264+tid]=(f16)a0; T[(x+1)*264+tid]=(f16)a1;
      T[(x+2)*264+tid]=(f16)a2; T[(x+3)*264+tid]=(f16)a3;
    }
  }
  __syncthreads();
  {
    int oct = tid & 31, pxl = tid >> 5;
    #pragma unroll
    for (int p=0;p<8;++p){
      int px = p*8 + pxl;
      *(uint4*)&dst[((size_t)((b*64+y)*64+px)<<8) + oct*8] = *(const uint4*)&T[px*264 + oct*8];
    }
  }
}

// ======================= QKV 1x1-conv GEMM (NHWC input) =======================
__global__ __launch_bounds__(256, 4) void k_qkv(
    const f16* __restrict__ xh,
    const f16* __restrict__ wq, const f16* __restrict__ wk, const f16* __restrict__ wv,
    const float* __restrict__ bq, const float* __restrict__ bk, const float* __restrict__ bv,
    const float* __restrict__ nq, const float* __restrict__ nk, const float* __restrict__ nv,
    f16* __restrict__ Qp, f16* __restrict__ Kp, f16* __restrict__ Vt)
{
  int idx = blockIdx.x;
  int yt  = idx & 15; idx >>= 4;
  int cot = idx & 3;  idx >>= 2;
  int b   = idx & 15; idx >>= 4;
  int sel = idx;
  int tid = threadIdx.x;
  int wave = tid>>6, lane = tid&63, quad = lane>>4, l16 = lane&15;
  int co0 = cot*64, y0 = yt*4;

  const f16*  W    = sel==0 ? wq : (sel==1 ? wk : wv);
  const float* bias= sel==0 ? bq : (sel==1 ? bk : bv);
  const float* nz  = sel==0 ? nq : (sel==1 ? nk : nv);

  __shared__ f16 smem[20480];

  f32x4 acc[16];
  #pragma unroll
  for (int i=0;i<16;++i){ acc[i][0]=0.f; acc[i][1]=0.f; acc[i][2]=0.f; acc[i][3]=0.f; }

  int g8 = (((lane&3) ^ ((lane>>3)&3)) << 3);
  const f16* Wrow = W + ((co0 + wave*16 + (lane>>2))<<8) + g8;
  const f16* Xrow = xh + (((size_t)((b*64 + y0)*64))<<8) + g8;

  auto stage = [&](int buf, int kc){
    int ci0 = kc<<5;
    f16* Ab = smem + buf*2048;
    f16* Bb = smem + 4096 + buf*8192;
    async_copy16(Wrow + ci0, Ab + wave*512);
    #pragma unroll
    for (int j=0;j<4;++j){
      int px = j*64 + wave*16 + (lane>>2);
      async_copy16(Xrow + ((size_t)px<<8) + ci0, Bb + (j*64 + wave*16)*32);
    }
  };

  stage(0, 0);
  #pragma unroll
  for (int kc=0; kc<8; ++kc){
    int cur = kc & 1;
    if (kc < 7){
      stage(cur^1, kc+1);
      asm volatile("s_waitcnt vmcnt(5)\n\ts_barrier" ::: "memory");
    } else {
      asm volatile("s_waitcnt vmcnt(0)\n\ts_barrier" ::: "memory");
    }
    const f16* Al = smem + cur*2048;
    const f16* Bl = smem + 4096 + cur*8192;
    f16x8 af = *(const f16x8*)&Al[(wave*16+l16)*32 + ((quad ^ ((l16>>1)&3))<<3)];
    #pragma unroll
    for (int nt=0;nt<16;++nt){
      int bidx = (nt>>2)*64 + (nt&3)*16 + l16;
      f16x8 bf = *(const f16x8*)&Bl[bidx*32 + ((quad ^ ((bidx>>1)&3))<<3)];
      acc[nt] = MFMA16(af, bf, acc[nt]);
    }
    asm volatile("s_waitcnt lgkmcnt(0)\n\ts_barrier" ::: "memory");
  }

  // ---- epilogue ----
  int cob = co0 + wave*16 + quad*4;
  int h0 = cot*4, pr = yt;
  float bs[4];
  #pragma unroll
  for (int r=0;r<4;++r) bs[r] = bias[cob+r];

  const float* nzb = nz + ((size_t)(b*256 + co0) << 12) + y0*64;

  #pragma unroll
  for (int half=0; half<2; ++half){
    #pragma unroll
    for (int p=0;p<8;++p){
      int i = p*256 + tid;
      int c32 = i>>6, px0 = (i&63)*4;
      float4 u = *(const float4*)(nzb + (((size_t)(half*32 + c32))<<12) + px0);
      f16x4 h4; h4[0]=(f16)u.x; h4[1]=(f16)u.y; h4[2]=(f16)u.z; h4[3]=(f16)u.w;
      *(f16x4*)&smem[c32*256 + (px0 ^ (((c32>>2)&3)<<4))] = h4;
    }
    __syncthreads();
    if ((wave>>1) == half){
      #pragma unroll
      for (int nt=0;nt<16;++nt){
        int px = (nt>>2)*64 + (nt&3)*16 + l16;
        int n_ = (nt&3)*4 + (l16>>2);
        int ddb = (quad<<6) + ((nt>>2)<<2) + (l16&3);
        #pragma unroll
        for (int r=0;r<4;++r){
          int c32 = ((wave&1)<<4) + (quad<<2) + r;
          float nzv = (float)smem[c32*256 + (px ^ (((c32>>2)&3)<<4))];
          float v = acc[nt][r] + bs[r] + nzv;
          int dd = ddb + (r<<4);
          if (sel < 2){
            int row = ((wave&1)<<4) + n_;
            smem[8192 + row*280 + dd + ((dd>>6)<<3)] = (f16)v;
          } else {
            smem[8192 + ((wave&1)*4128) + dd*16 + ((dd>>6)<<3) + n_] = (f16)v;
          }
        }
      }
    }
    __syncthreads();
    if (sel < 2){
      f16* dst = sel==0 ? Qp : Kp;
      #pragma unroll
      for (int pass=0; pass<4; ++pass){
        int rowi = pass*8 + (tid>>5);
        int ch  = tid & 31;
        uint4 v = *(const uint4*)&smem[8192 + rowi*280 + ch*8 + ((ch>>3)<<3)];
        int grow = half*32 + rowi;
        *(uint4*)&dst[((b*16 + h0 + (grow>>4))<<16) + ((pr*16 + (grow&15))<<8) + ch*8] = v;
      }
    } else {
      #pragma unroll
      for (int p=0;p<4;++p){
        int i = p*256 + tid;
        int rw = i>>1, hf = i&1;
        int dd = rw & 255;
        uint4 v = *(const uint4*)&smem[8192 + (rw>>8)*4128 + dd*16 + ((dd>>6)<<3) + hf*8];
        *(uint4*)&Vt[((b*16 + h0 + half*2 + (rw>>8))<<16) + (dd<<8) + pr*16 + hf*8] = v;
      }
    }
    __syncthreads();
  }
}

// ======================= attention =======================
__global__ __launch_bounds__(256) void k_attn(
    const f16* __restrict__ Qp, const f16* __restrict__ Kp, const f16* __restrict__ Vt,
    const float* __restrict__ dis, const float* __restrict__ lap_a,
    const float* __restrict__ pm, f16* __restrict__ attn)
{
  int idx = blockIdx.x;
  int nt = idx & 3; idx >>= 2;
  int h  = idx & 15; idx >>= 4;
  int b  = idx;
  int tid = threadIdx.x, wave = tid>>6, lane = tid&63, quad = lane>>4, l16 = lane&15;
  int n0 = nt*64;
  int bh = (b*16 + h) << 16;

  __shared__ f16 smem[25344];
  f16* Ql  = smem;
  f16* KVl = smem + 16896;

  {
    int row = tid>>2, part = (tid&3)*64;
    const uint4* s = (const uint4*)&Qp[bh + ((n0+row)<<8) + part];
    uint4* d = (uint4*)&Ql[row*264 + part];
    #pragma unroll
    for (int j=0;j<8;++j) d[j] = s[j];
  }

  float splus = log1pf(expf(lap_a[0]));

  f32x4 sacc[16];
  #pragma unroll
  for (int i=0;i<16;++i){ sacc[i][0]=0.f; sacc[i][1]=0.f; sacc[i][2]=0.f; sacc[i][3]=0.f; }

  #pragma unroll
  for (int mc=0; mc<8; ++mc){
    __syncthreads();
    {
      int row = tid>>3, part = (tid&7)*32;
      const uint4* s = (const uint4*)&Kp[bh + ((mc*32+row)<<8) + part];
      uint4* d = (uint4*)&KVl[row*264 + part];
      #pragma unroll
      for (int j=0;j<4;++j) d[j] = s[j];
    }
    __syncthreads();
    #pragma unroll
    for (int kk=0;kk<8;++kk){
      f16x8 af = *(const f16x8*)&Ql[(wave*16+l16)*264 + kk*32 + quad*8];
      #pragma unroll
      for (int j=0;j<2;++j){
        f16x8 bf = *(const f16x8*)&KVl[(j*16+l16)*264 + kk*32 + quad*8];
        sacc[mc*2+j] = MFMA16(af, bf, sacc[mc*2+j]);
      }
    }
  }

  int nrow_base = wave*16 + quad*4;
  float pmv[16];
  #pragma unroll
  for (int t=0;t<16;++t) pmv[t] = pm[b*256 + t*16 + l16];

  #pragma unroll
  for (int r=0;r<4;++r){
    int n = n0 + nrow_base + r;
    float sv[16];
    float mx = -1e30f;
    #pragma unroll
    for (int t=0;t<16;++t){
      float s = sacc[t][r];
      s = (s + splus * dis[n*256 + t*16 + l16]) * 0.0625f;
      s = (pmv[t] > 0.5f) ? -1e30f : s;
      sv[t] = s;
      mx = fmaxf(mx, s);
    }
    #pragma unroll
    for (int off=1; off<16; off<<=1) mx = fmaxf(mx, __shfl_xor(mx, off, 64));
    float sum = 0.f;
    #pragma unroll
    for (int t=0;t<16;++t){ float e = __expf(sv[t]-mx); sv[t]=e; sum += e; }
    #pragma unroll
    for (int off=1; off<16; off<<=1) sum += __shfl_xor(sum, off, 64);
    float inv = 1.f/sum;
    #pragma unroll
    for (int t=0;t<16;++t) Ql[(nrow_base + r)*264 + t*16 + l16] = (f16)(sv[t]*inv);
  }

  f32x4 oacc[16];
  #pragma unroll
  for (int i=0;i<16;++i){ oacc[i][0]=0.f; oacc[i][1]=0.f; oacc[i][2]=0.f; oacc[i][3]=0.f; }

  for (int dc=0; dc<8; ++dc){
    __syncthreads();
    {
      int row = tid>>3, part = (tid&7)*32;
      const uint4* s = (const uint4*)&Vt[bh + ((dc*32+row)<<8) + part];
      uint4* d = (uint4*)&KVl[row*264 + part];
      #pragma unroll
      for (int j=0;j<4;++j) d[j] = s[j];
    }
    __syncthreads();
    #pragma unroll
    for (int kk=0;kk<8;++kk){
      f16x8 af = *(const f16x8*)&Ql[(wave*16+l16)*264 + kk*32 + quad*8];
      #pragma unroll
      for (int j=0;j<2;++j){
        f16x8 bf = *(const f16x8*)&KVl[(j*16+l16)*264 + kk*32 + quad*8];
        oacc[dc*2+j] = MFMA16(af, bf, oacc[dc*2+j]);
      }
    }
  }

  __syncthreads();
  #pragma unroll
  for (int dc=0; dc<8; ++dc){
    #pragma unroll
    for (int j=0;j<2;++j){
      int dd = dc*32 + j*16 + l16;
      int c_ = dd>>4;
      int pi = (dd>>2)&3, pj = dd&3;
      #pragma unroll
      for (int r=0;r<4;++r){
        int nl = nrow_base + r;
        int y_ = ((nl>>4)<<2) + pi;
        int x  = ((nl&15)<<2) + pj;
        smem[(y_*64 + x)*24 + c_] = (f16)oacc[dc*2+j][r];
      }
    }
  }
  __syncthreads();
  #pragma unroll
  for (int p=0;p<4;++p){
    int pix = p*256 + tid;
    int y_ = pix>>6, x = pix&63;
    uint4 v0 = *(const uint4*)&smem[pix*24];
    uint4 v1 = *(const uint4*)&smem[pix*24 + 8];
    size_t o = ((size_t)((b*64 + nt*16 + y_)*64 + x)<<8) + h*16;
    *(uint4*)&attn[o]     = v0;
    *(uint4*)&attn[o + 8] = v1;
  }
}

// ======================= 3x3 conv (implicit GEMM, NHWC input) ================
// Async dbuf B-staging (source-preswizzled, zero-page halo), weights direct to
// regs (L2-resident), one barrier per (ky,kc) iteration.
template<int DIL, int MODE>
__global__ __launch_bounds__(256, 4) void k_conv3(
    const f16* __restrict__ in, const f16* __restrict__ Wt, const float* __restrict__ bias,
    const float* __restrict__ resid, float* __restrict__ outf, f16* __restrict__ outh,
    const float* __restrict__ zp)
{
  int idx = blockIdx.x;
  int yt  = idx & 15; idx >>= 4;
  int cot = idx & 3;  idx >>= 2;
  int b   = idx;
  int y0 = yt*4, co0 = cot*64;
  int tid = threadIdx.x;
  int wave = tid>>6, lane = tid&63, quad = lane>>4, l16 = lane&15;

  // LDS 35840B: B dbuf 2 x (272 rows x 32ci f16 = 17408B) + 1024B DMA dump.
  // MODE0 epilogue reuses first 32768B as float cs4[8192].
  __shared__ f16 smem[17920];

  f32x4 acc[16];
  #pragma unroll
  for (int i=0;i<16;++i){ acc[i][0]=0.f; acc[i][1]=0.f; acc[i][2]=0.f; acc[i][3]=0.f; }

  const f16* zp16 = (const f16*)zp;
  int oct = (lane&3) ^ ((lane>>3)&3);
  int rl  = lane>>2;
  const f16* wbase = Wt + ((co0 + wave*16 + l16)<<8) + quad*8;

  // stage B tile (4 rows x 68 px x 32 ci) for iteration (ky,kc): rows si = yr*68+xp,
  // LDS slot s of row si holds ci-oct s ^ ((si>>1)&3)  -> 2-way-free ds_read_b128.
  auto stageB = [&](int buf, int ky, int kc){
    int ci0 = kc<<5;
    int ybase = y0 + DIL*(ky-1);
    f16* Bb = smem + buf*8704;
    #pragma unroll
    for (int j=0;j<5;++j){
      int si = j*64 + wave*16 + rl;                  // 0..319 (>=272 -> dump)
      int yr = si / 68;
      int xp = si - yr*68;
      int yy = ybase + yr, xx = xp - DIL;
      bool valid = (si < 272) && (yy>=0) && (yy<64) && (xx>=0) && (xx<64);
      const f16* src = valid ? &in[((size_t)((b*64+yy)*64+xx)<<8) + ci0 + oct*8] : zp16;
      f16* dst = (j==4 && wave!=0) ? (smem + 17408) : (Bb + (j*64 + wave*16)*32);
      async_copy16(src, dst);
    }
  };

  f16x8 afc[3], afn[3];
  #pragma unroll
  for (int kx=0;kx<3;++kx){ afc[kx] = *(const f16x8*)&wbase[kx<<16]; afn[kx] = afc[kx]; }
  stageB(0, 0, 0);

  for (int t=0; t<24; ++t){
    int cur = t & 1;
    asm volatile("s_waitcnt vmcnt(0)\n\ts_barrier" ::: "memory");
    if (t < 23){
      int tn = t+1, kyn = tn>>3, kcn = tn&7;
      stageB(cur^1, kyn, kcn);
      #pragma unroll
      for (int kx=0;kx<3;++kx)
        afn[kx] = *(const f16x8*)&wbase[((kyn*3+kx)<<16) + (kcn<<5)];
    }
    const f16* Bl = smem + cur*8704;
    #pragma unroll
    for (int kx=0;kx<3;++kx){
      #pragma unroll
      for (int nt=0;nt<16;++nt){
        int bidx = (nt>>2)*68 + (nt&3)*16 + l16 + kx*DIL;
        f16x8 bf = *(const f16x8*)&Bl[bidx*32 + ((quad ^ ((bidx>>1)&3))<<3)];
        acc[nt] = MFMA16(afc[kx], bf, acc[nt]);
      }
    }
    #pragma unroll
    for (int kx=0;kx<3;++kx) afc[kx] = afn[kx];
  }
  asm volatile("s_waitcnt lgkmcnt(0)\n\ts_barrier" ::: "memory");

  int cob = co0 + wave*16 + quad*4;
  float bs[4];
  #pragma unroll
  for (int r=0;r<4;++r) bs[r] = bias[cob+r];

  if (MODE==0){
    float* cs4 = (float*)smem;
    const float* rb = resid + ((size_t)(b*256 + co0) << 12) + y0*64;
    #pragma unroll
    for (int half=0; half<2; ++half){
      #pragma unroll
      for (int p=0;p<8;++p){
        int i = p*256 + tid;
        int c32 = i>>6, px0 = (i&63)*4;
        float4 u = *(const float4*)(rb + (((size_t)(half*32 + c32))<<12) + px0);
        *(float4*)&cs4[c32*256 + (px0 ^ (((c32>>2)&3)<<3))] = u;
      }
      __syncthreads();
      if ((wave>>1) == half){
        #pragma unroll
        for (int nt=0;nt<16;++nt){
          int y = y0 + (nt>>2), x = (nt&3)*16 + l16;
          int px = (nt>>2)*64 + (nt&3)*16 + l16;
          #pragma unroll
          for (int r=0;r<4;++r){
            int co = cob + r;
            int c32 = ((wave&1)<<4) + (quad<<2) + r;
            float rv = cs4[c32*256 + (px ^ (((c32>>2)&3)<<3))];
            float v = lrelu(acc[nt][r] + bs[r]) + rv;
            size_t o = (size_t)(b*256+co)*4096 + y*64 + x;
            outf[o] = v;
            outh[((size_t)((b*64+y)*64+x)<<8) + co] = (f16)v;
          }
        }
      }
      __syncthreads();
    }
  } else {
    #pragma unroll
    for (int nt=0;nt<16;++nt){
      int y = y0 + (nt>>2), x = (nt&3)*16 + l16;
      #pragma unroll
      for (int r=0;r<4;++r){
        int co = cob + r;
        float v = acc[nt][r] + bs[r];
        size_t o = (size_t)(b*256+co)*4096 + y*64 + x;
        outf[o] = v;
      }
    }
  }
}

// ======================= instance-norm stats (NCHW f32) =======================
__global__ __launch_bounds__(256) void k_instats(const float* __restrict__ v, float2* __restrict__ st)
{
  int bc = blockIdx.x;
  const float* p = v + (size_t)bc*4096;
  int tid = threadIdx.x;
  float s=0.f, ss=0.f;
  #pragma unroll
  for (int it=0; it<4; ++it){
    float4 u = *(const float4*)(p + it*1024 + tid*4);
    s  += u.x+u.y+u.z+u.w;
    ss += u.x*u.x + u.y*u.y + u.z*u.z + u.w*u.w;
  }
  #pragma unroll
  for (int off=32; off; off>>=1){ s += __shfl_down(s, off, 64); ss += __shfl_down(ss, off, 64); }
  __shared__ float rs[4], rss[4];
  int wave = tid>>6, lane = tid&63;
  if (lane==0){ rs[wave]=s; rss[wave]=ss; }
  __syncthreads();
  if (tid==0){
    float S = rs[0]+rs[1]+rs[2]+rs[3], SS = rss[0]+rss[1]+rss[2]+rss[3];
    float mu = S*(1.f/4096.f);
    float var = SS*(1.f/4096.f) - mu*mu;
    st[bc] = make_float2(mu, rsqrtf(var + 1e-5f));
  }
}

// final: out += lrelu(IN(c2))
__global__ __launch_bounds__(256) void k_final(float* __restrict__ out, const float* __restrict__ c2,
                                               const float2* __restrict__ st)
{
  int i4 = blockIdx.x*256 + threadIdx.x;
  float2 s = st[i4>>10];
  float4 u = *(const float4*)(c2 + (size_t)i4*4);
  float4 o = *(const float4*)(out + (size_t)i4*4);
  o.x += lrelu((u.x - s.x)*s.y);
  o.y += lrelu((u.y - s.x)*s.y);
  o.z += lrelu((u.z - s.x)*s.y);
  o.w += lrelu((u.w - s.x)*s.y);
  *(float4*)(out + (size_t)i4*4) = o;
}

// ======================= launch =======================
extern "C" void kernel_launch(void* const* d_in, const int* in_sizes, int n_in,
                              void* d_out, int out_size, void* d_ws, size_t ws_size,
                              hipStream_t stream)
{
  const float* x    = (const float*)d_in[0];
  const float* mask = (const float*)d_in[1];
  const float* dis  = (const float*)d_in[2];
  const float* lapa = (const float*)d_in[3];
  const float* Wq   = (const float*)d_in[4];
  const float* bq   = (const float*)d_in[5];
  const float* Wk   = (const float*)d_in[6];
  const float* bk   = (const float*)d_in[7];
  const float* Wv   = (const float*)d_in[8];
  const float* bv   = (const float*)d_in[9];
  const float* nq   = (const float*)d_in[10];
  const float* nk   = (const float*)d_in[11];
  const float* nv   = (const float*)d_in[12];
  const float* Wo   = (const float*)d_in[13];
  const float* bo   = (const float*)d_in[14];
  const float* W1   = (const float*)d_in[15];
  const float* b1   = (const float*)d_in[16];
  const float* W2   = (const float*)d_in[17];
  const float* b2   = (const float*)d_in[18];

  char* w = (char*)d_ws;
  f16*   xh    = (f16*)(w + 0);
  f16*   Qp    = (f16*)(w + 33554432);
  f16*   Kp    = (f16*)(w + 67108864);
  f16*   Vt    = (f16*)(w + 100663296);
  f16*   attnb = (f16*)(w + 134217728);
  f16*   outbf = (f16*)(w + 0);
  float* c1    = (float*)(w + 33554432);
  f16*   y1    = (f16*)(w + 100663296);
  float* c2    = (float*)(w + 33554432);
  f16*   wqh   = (f16*)(w + 167772160);
  f16*   wkh   = wqh + 65536;
  f16*   wvh   = wkh + 65536;
  f16*   wt0   = (f16*)(w + 168165376);
  f16*   wt1   = wt0 + 589824;
  f16*   wt2   = wt1 + 589824;
  float* pmk   = (float*)(w + 171704320);
  float2* st1  = (float2*)(w + 171720704);
  float2* st2  = (float2*)(w + 171753472);
  float* zpk   = (float*)(w + 171786240);
  float* out   = (float*)d_out;

  k_prep1x1<<<768, 256, 0, stream>>>(Wq, Wk, Wv, wqh, wkh, wvh);
  k_prep3x3<<<6912, 256, 0, stream>>>(Wo, W1, W2, wt0, wt1, wt2);
  k_pmask<<<16, 256, 0, stream>>>(mask, pmk, zpk);
  k_nchw2nhwc<<<1024, 256, 0, stream>>>(x, nullptr, xh);
  k_qkv<<<3072, 256, 0, stream>>>(xh, wqh, wkh, wvh, bq, bk, bv, nq, nk, nv, Qp, Kp, Vt);
  k_attn<<<1024, 256, 0, stream>>>(Qp, Kp, Vt, dis, lapa, pmk, attnb);
  k_conv3<1,0><<<1024, 256, 0, stream>>>(attnb, wt0, bo, x, out, outbf, zpk);
  k_conv3<2,1><<<1024, 256, 0, stream>>>(outbf, wt1, b1, nullptr, c1, nullptr, zpk);
  k_instats<<<4096, 256, 0, stream>>>(c1, st1);
  k_nchw2nhwc<<<1024, 256, 0, stream>>>(c1, st1, y1);
  k_conv3<1,1><<<1024, 256, 0, stream>>>(y1, wt2, b2, nullptr, c2, nullptr, zpk);
  k_instats<<<4096, 256, 0, stream>>>(c2, st2);
  k_final<<<16384, 256, 0, stream>>>(out, c2, st2);
}

// Round 5
// 963.540 us; speedup vs baseline: 1.5743x; 1.5743x over previous
//
#include <hip/hip_runtime.h>
#include <cstdint>
#include <cstddef>

typedef _Float16 f16;
typedef _Float16 f16x8 __attribute__((ext_vector_type(8)));
typedef _Float16 f16x4 __attribute__((ext_vector_type(4)));
typedef float    f32x4 __attribute__((ext_vector_type(4)));

#define MFMA16(a,b,c) __builtin_amdgcn_mfma_f32_16x16x32_f16((a),(b),(c),0,0,0)

__device__ __forceinline__ float lrelu(float v){ return v >= 0.f ? v : 0.2f*v; }

// async global->LDS 16B copy; global addr per-lane, LDS dest = wave base + lane*16
__device__ __forceinline__ void async_copy16(const f16* g, f16* l){
  __builtin_amdgcn_global_load_lds(
      (const __attribute__((address_space(1))) void*)(uintptr_t)(const void*)g,
      (__attribute__((address_space(3))) void*)(uint32_t)(uintptr_t)(void*)l,
      16, 0, 0);
}

// ======================= prep kernels =======================

__global__ __launch_bounds__(256) void k_prep1x1(
    const float* __restrict__ wq, const float* __restrict__ wk, const float* __restrict__ wv,
    f16* __restrict__ oq, f16* __restrict__ ok, f16* __restrict__ ov)
{
  int i = blockIdx.x*256 + threadIdx.x;
  int sel = i >> 16, r = i & 65535;
  const float* s = sel==0 ? wq : (sel==1 ? wk : wv);
  f16* d = sel==0 ? oq : (sel==1 ? ok : ov);
  d[r] = (f16)s[r];
}

// 3x3 conv weights (co,ci,3,3) fp32 -> fp16 layout [tap][co][ci]
__global__ __launch_bounds__(256) void k_prep3x3(
    const float* __restrict__ w0, const float* __restrict__ w1, const float* __restrict__ w2,
    f16* __restrict__ o0, f16* __restrict__ o1, f16* __restrict__ o2)
{
  int i = blockIdx.x*256 + threadIdx.x;
  int sel = i / 589824;
  int r = i - sel*589824;
  int t = r >> 16; int rr = r & 65535; int co = rr >> 8; int ci = rr & 255;
  const float* s = sel==0 ? w0 : (sel==1 ? w1 : w2);
  f16* d = sel==0 ? o0 : (sel==1 ? o1 : o2);
  d[r] = (f16)s[(co*256 + ci)*9 + t];
}

__global__ __launch_bounds__(256) void k_pmask(const float* __restrict__ mask, float* __restrict__ pm)
{
  int t = blockIdx.x*256 + threadIdx.x;
  int b = t >> 8, n = t & 255;
  int y0 = (n>>4)<<2, x0 = (n&15)<<2;
  const float* mb = mask + b*4096;
  float s = 0.f;
  #pragma unroll
  for (int i=0;i<4;++i)
    #pragma unroll
    for (int j=0;j<4;++j) s += mb[(y0+i)*64 + x0+j];
  pm[t] = (s*(1.f/16.f) < 0.5f) ? 1.f : 0.f;
}

// ======================= NCHW f32 -> NHWC f16 (optional IN+lrelu) ===========
__global__ __launch_bounds__(256) void k_nchw2nhwc(
    const float* __restrict__ src, const float2* __restrict__ st, f16* __restrict__ dst)
{
  int idx = blockIdx.x;
  int y = idx & 63, b = idx >> 6;
  int tid = threadIdx.x;
  __shared__ f16 T[64*264];

  {
    const float* row = src + (size_t)(b*256+tid)*4096 + y*64;
    float mu = 0.f, ri = 1.f;
    bool doin = (st != nullptr);
    if (doin){ float2 s = st[b*256+tid]; mu = s.x; ri = s.y; }
    #pragma unroll
    for (int j=0;j<16;++j){
      float4 u = *(const float4*)(row + j*4);
      int x = j*4;
      float a0=(u.x-mu)*ri, a1=(u.y-mu)*ri, a2=(u.z-mu)*ri, a3=(u.w-mu)*ri;
      if (doin){ a0=lrelu(a0); a1=lrelu(a1); a2=lrelu(a2); a3=lrelu(a3); }
      T[(x+0)*264+tid]=(f16)a0; T[(x+1)*264+tid]=(f16)a1;
      T[(x+2)*264+tid]=(f16)a2; T[(x+3)*264+tid]=(f16)a3;
    }
  }
  __syncthreads();
  {
    int oct = tid & 31, pxl = tid >> 5;
    #pragma unroll
    for (int p=0;p<8;++p){
      int px = p*8 + pxl;
      *(uint4*)&dst[((size_t)((b*64+y)*64+px)<<8) + oct*8] = *(const uint4*)&T[px*264 + oct*8];
    }
  }
}

// ======================= QKV 1x1-conv GEMM (NHWC input) =======================
__global__ __launch_bounds__(256, 4) void k_qkv(
    const f16* __restrict__ xh,
    const f16* __restrict__ wq, const f16* __restrict__ wk, const f16* __restrict__ wv,
    const float* __restrict__ bq, const float* __restrict__ bk, const float* __restrict__ bv,
    const float* __restrict__ nq, const float* __restrict__ nk, const float* __restrict__ nv,
    f16* __restrict__ Qp, f16* __restrict__ Kp, f16* __restrict__ Vt)
{
  int idx = blockIdx.x;
  int yt  = idx & 15; idx >>= 4;
  int cot = idx & 3;  idx >>= 2;
  int b   = idx & 15; idx >>= 4;
  int sel = idx;
  int tid = threadIdx.x;
  int wave = tid>>6, lane = tid&63, quad = lane>>4, l16 = lane&15;
  int co0 = cot*64, y0 = yt*4;

  const f16*  W    = sel==0 ? wq : (sel==1 ? wk : wv);
  const float* bias= sel==0 ? bq : (sel==1 ? bk : bv);
  const float* nz  = sel==0 ? nq : (sel==1 ? nk : nv);

  __shared__ f16 smem[20480];

  f32x4 acc[16];
  #pragma unroll
  for (int i=0;i<16;++i){ acc[i][0]=0.f; acc[i][1]=0.f; acc[i][2]=0.f; acc[i][3]=0.f; }

  int g8 = (((lane&3) ^ ((lane>>3)&3)) << 3);
  const f16* Wrow = W + ((co0 + wave*16 + (lane>>2))<<8) + g8;
  const f16* Xrow = xh + (((size_t)((b*64 + y0)*64))<<8) + g8;

  auto stage = [&](int buf, int kc){
    int ci0 = kc<<5;
    f16* Ab = smem + buf*2048;
    f16* Bb = smem + 4096 + buf*8192;
    async_copy16(Wrow + ci0, Ab + wave*512);
    #pragma unroll
    for (int j=0;j<4;++j){
      int px = j*64 + wave*16 + (lane>>2);
      async_copy16(Xrow + ((size_t)px<<8) + ci0, Bb + (j*64 + wave*16)*32);
    }
  };

  stage(0, 0);
  #pragma unroll
  for (int kc=0; kc<8; ++kc){
    int cur = kc & 1;
    if (kc < 7){
      stage(cur^1, kc+1);
      asm volatile("s_waitcnt vmcnt(5)\n\ts_barrier" ::: "memory");
    } else {
      asm volatile("s_waitcnt vmcnt(0)\n\ts_barrier" ::: "memory");
    }
    const f16* Al = smem + cur*2048;
    const f16* Bl = smem + 4096 + cur*8192;
    f16x8 af = *(const f16x8*)&Al[(wave*16+l16)*32 + ((quad ^ ((l16>>1)&3))<<3)];
    #pragma unroll
    for (int nt=0;nt<16;++nt){
      int bidx = (nt>>2)*64 + (nt&3)*16 + l16;
      f16x8 bf = *(const f16x8*)&Bl[bidx*32 + ((quad ^ ((bidx>>1)&3))<<3)];
      acc[nt] = MFMA16(af, bf, acc[nt]);
    }
    asm volatile("s_waitcnt lgkmcnt(0)\n\ts_barrier" ::: "memory");
  }

  // ---- epilogue ----
  int cob = co0 + wave*16 + quad*4;
  int h0 = cot*4, pr = yt;
  float bs[4];
  #pragma unroll
  for (int r=0;r<4;++r) bs[r] = bias[cob+r];

  const float* nzb = nz + ((size_t)(b*256 + co0) << 12) + y0*64;

  #pragma unroll
  for (int half=0; half<2; ++half){
    #pragma unroll
    for (int p=0;p<8;++p){
      int i = p*256 + tid;
      int c32 = i>>6, px0 = (i&63)*4;
      float4 u = *(const float4*)(nzb + (((size_t)(half*32 + c32))<<12) + px0);
      f16x4 h4; h4[0]=(f16)u.x; h4[1]=(f16)u.y; h4[2]=(f16)u.z; h4[3]=(f16)u.w;
      *(f16x4*)&smem[c32*256 + (px0 ^ (((c32>>2)&3)<<4))] = h4;
    }
    __syncthreads();
    if ((wave>>1) == half){
      #pragma unroll
      for (int nt=0;nt<16;++nt){
        int px = (nt>>2)*64 + (nt&3)*16 + l16;
        int n_ = (nt&3)*4 + (l16>>2);
        int ddb = (quad<<6) + ((nt>>2)<<2) + (l16&3);
        #pragma unroll
        for (int r=0;r<4;++r){
          int c32 = ((wave&1)<<4) + (quad<<2) + r;
          float nzv = (float)smem[c32*256 + (px ^ (((c32>>2)&3)<<4))];
          float v = acc[nt][r] + bs[r] + nzv;
          int dd = ddb + (r<<4);
          if (sel < 2){
            int row = ((wave&1)<<4) + n_;
            smem[8192 + row*280 + dd + ((dd>>6)<<3)] = (f16)v;
          } else {
            smem[8192 + ((wave&1)*4128) + dd*16 + ((dd>>6)<<3) + n_] = (f16)v;
          }
        }
      }
    }
    __syncthreads();
    if (sel < 2){
      f16* dst = sel==0 ? Qp : Kp;
      #pragma unroll
      for (int pass=0; pass<4; ++pass){
        int rowi = pass*8 + (tid>>5);
        int ch  = tid & 31;
        uint4 v = *(const uint4*)&smem[8192 + rowi*280 + ch*8 + ((ch>>3)<<3)];
        int grow = half*32 + rowi;
        *(uint4*)&dst[((b*16 + h0 + (grow>>4))<<16) + ((pr*16 + (grow&15))<<8) + ch*8] = v;
      }
    } else {
      #pragma unroll
      for (int p=0;p<4;++p){
        int i = p*256 + tid;
        int rw = i>>1, hf = i&1;
        int dd = rw & 255;
        uint4 v = *(const uint4*)&smem[8192 + (rw>>8)*4128 + dd*16 + ((dd>>6)<<3) + hf*8];
        *(uint4*)&Vt[((b*16 + h0 + half*2 + (rw>>8))<<16) + (dd<<8) + pr*16 + hf*8] = v;
      }
    }
    __syncthreads();
  }
}

// ======================= attention =======================
__global__ __launch_bounds__(256) void k_attn(
    const f16* __restrict__ Qp, const f16* __restrict__ Kp, const f16* __restrict__ Vt,
    const float* __restrict__ dis, const float* __restrict__ lap_a,
    const float* __restrict__ pm, f16* __restrict__ attn)
{
  int idx = blockIdx.x;
  int nt = idx & 3; idx >>= 2;
  int h  = idx & 15; idx >>= 4;
  int b  = idx;
  int tid = threadIdx.x, wave = tid>>6, lane = tid&63, quad = lane>>4, l16 = lane&15;
  int n0 = nt*64;
  int bh = (b*16 + h) << 16;

  __shared__ f16 smem[25344];
  f16* Ql  = smem;
  f16* KVl = smem + 16896;

  {
    int row = tid>>2, part = (tid&3)*64;
    const uint4* s = (const uint4*)&Qp[bh + ((n0+row)<<8) + part];
    uint4* d = (uint4*)&Ql[row*264 + part];
    #pragma unroll
    for (int j=0;j<8;++j) d[j] = s[j];
  }

  float splus = log1pf(expf(lap_a[0]));

  f32x4 sacc[16];
  #pragma unroll
  for (int i=0;i<16;++i){ sacc[i][0]=0.f; sacc[i][1]=0.f; sacc[i][2]=0.f; sacc[i][3]=0.f; }

  #pragma unroll
  for (int mc=0; mc<8; ++mc){
    __syncthreads();
    {
      int row = tid>>3, part = (tid&7)*32;
      const uint4* s = (const uint4*)&Kp[bh + ((mc*32+row)<<8) + part];
      uint4* d = (uint4*)&KVl[row*264 + part];
      #pragma unroll
      for (int j=0;j<4;++j) d[j] = s[j];
    }
    __syncthreads();
    #pragma unroll
    for (int kk=0;kk<8;++kk){
      f16x8 af = *(const f16x8*)&Ql[(wave*16+l16)*264 + kk*32 + quad*8];
      #pragma unroll
      for (int j=0;j<2;++j){
        f16x8 bf = *(const f16x8*)&KVl[(j*16+l16)*264 + kk*32 + quad*8];
        sacc[mc*2+j] = MFMA16(af, bf, sacc[mc*2+j]);
      }
    }
  }

  int nrow_base = wave*16 + quad*4;
  float pmv[16];
  #pragma unroll
  for (int t=0;t<16;++t) pmv[t] = pm[b*256 + t*16 + l16];

  #pragma unroll
  for (int r=0;r<4;++r){
    int n = n0 + nrow_base + r;
    float sv[16];
    float mx = -1e30f;
    #pragma unroll
    for (int t=0;t<16;++t){
      float s = sacc[t][r];
      s = (s + splus * dis[n*256 + t*16 + l16]) * 0.0625f;
      s = (pmv[t] > 0.5f) ? -1e30f : s;
      sv[t] = s;
      mx = fmaxf(mx, s);
    }
    #pragma unroll
    for (int off=1; off<16; off<<=1) mx = fmaxf(mx, __shfl_xor(mx, off, 64));
    float sum = 0.f;
    #pragma unroll
    for (int t=0;t<16;++t){ float e = __expf(sv[t]-mx); sv[t]=e; sum += e; }
    #pragma unroll
    for (int off=1; off<16; off<<=1) sum += __shfl_xor(sum, off, 64);
    float inv = 1.f/sum;
    #pragma unroll
    for (int t=0;t<16;++t) Ql[(nrow_base + r)*264 + t*16 + l16] = (f16)(sv[t]*inv);
  }

  f32x4 oacc[16];
  #pragma unroll
  for (int i=0;i<16;++i){ oacc[i][0]=0.f; oacc[i][1]=0.f; oacc[i][2]=0.f; oacc[i][3]=0.f; }

  for (int dc=0; dc<8; ++dc){
    __syncthreads();
    {
      int row = tid>>3, part = (tid&7)*32;
      const uint4* s = (const uint4*)&Vt[bh + ((dc*32+row)<<8) + part];
      uint4* d = (uint4*)&KVl[row*264 + part];
      #pragma unroll
      for (int j=0;j<4;++j) d[j] = s[j];
    }
    __syncthreads();
    #pragma unroll
    for (int kk=0;kk<8;++kk){
      f16x8 af = *(const f16x8*)&Ql[(wave*16+l16)*264 + kk*32 + quad*8];
      #pragma unroll
      for (int j=0;j<2;++j){
        f16x8 bf = *(const f16x8*)&KVl[(j*16+l16)*264 + kk*32 + quad*8];
        oacc[dc*2+j] = MFMA16(af, bf, oacc[dc*2+j]);
      }
    }
  }

  __syncthreads();
  #pragma unroll
  for (int dc=0; dc<8; ++dc){
    #pragma unroll
    for (int j=0;j<2;++j){
      int dd = dc*32 + j*16 + l16;
      int c_ = dd>>4;
      int pi = (dd>>2)&3, pj = dd&3;
      #pragma unroll
      for (int r=0;r<4;++r){
        int nl = nrow_base + r;
        int y_ = ((nl>>4)<<2) + pi;
        int x  = ((nl&15)<<2) + pj;
        smem[(y_*64 + x)*24 + c_] = (f16)oacc[dc*2+j][r];
      }
    }
  }
  __syncthreads();
  #pragma unroll
  for (int p=0;p<4;++p){
    int pix = p*256 + tid;
    int y_ = pix>>6, x = pix&63;
    uint4 v0 = *(const uint4*)&smem[pix*24];
    uint4 v1 = *(const uint4*)&smem[pix*24 + 8];
    size_t o = ((size_t)((b*64 + nt*16 + y_)*64 + x)<<8) + h*16;
    *(uint4*)&attn[o]     = v0;
    *(uint4*)&attn[o + 8] = v1;
  }
}

// ======================= 3x3 conv (implicit GEMM, NHWC input) ================
// Round-3 structure (VGPR-staged B + ds_write, LDS weights); only change:
// B-tile LDS swizzle (si&3) -> ((si>>1)&3) on write+read = conflict-free b128.
template<int DIL, int MODE>
__global__ __launch_bounds__(256) void k_conv3(
    const f16* __restrict__ in, const f16* __restrict__ Wt, const float* __restrict__ bias,
    const float* __restrict__ resid, float* __restrict__ outf, f16* __restrict__ outh)
{
  int idx = blockIdx.x;
  int yt  = idx & 15; idx >>= 4;
  int cot = idx & 3;  idx >>= 2;
  int b   = idx;
  int y0 = yt*4, co0 = cot*64;
  int tid = threadIdx.x;
  int wave = tid>>6, lane = tid&63, quad = lane>>4, l16 = lane&15;

  // 32768B shared: K-loop Al [0,7680) f16, Bl [7680,16384) f16.
  // MODE0 epilogue: resid f32 [32c][256px] swizzled (two halves).
  __shared__ float cs4[8192];
  f16* Al = (f16*)cs4;
  f16* Bl = (f16*)cs4 + 7680;

  f32x4 acc[16];
  #pragma unroll
  for (int i=0;i<16;++i){ acc[i][0]=0.f; acc[i][1]=0.f; acc[i][2]=0.f; acc[i][3]=0.f; }

  constexpr int PXR = 64 + 2*DIL;
  constexpr int NU4 = 16*PXR;

  for (int ky=0; ky<3; ++ky){
    int yb = y0 + DIL*(ky-1);
    for (int kc=0; kc<8; ++kc){
      int ci0 = kc*32;
      {
        int aco = tid>>2, ap = (tid&3)*8;
        #pragma unroll
        for (int kx=0;kx<3;++kx)
          *(uint4*)&Al[kx*2560 + aco*40 + ap] =
              *(const uint4*)&Wt[((ky*3+kx)<<16) + ((co0+aco)<<8) + ci0 + ap];
      }
      #pragma unroll
      for (int p=0;p<5;++p){
        int i = p*256 + tid;
        if (i < NU4){
          int px = i>>2, oct = i&3;
          int yr = px / PXR, xp = px - yr*PXR;
          int yy = yb + yr, xx = xp - DIL;
          uint4 v = make_uint4(0u,0u,0u,0u);
          if (yy>=0 && yy<64 && xx>=0 && xx<64)
            v = *(const uint4*)&in[((size_t)((b*64+yy)*64+xx)<<8) + ci0 + oct*8];
          int si = yr*68 + xp;
          *(uint4*)&Bl[si*32 + ((oct ^ ((si>>1)&3))<<3)] = v;
        }
      }
      __syncthreads();
      #pragma unroll
      for (int kx=0;kx<3;++kx){
        f16x8 af = *(const f16x8*)&Al[kx*2560 + (wave*16+l16)*40 + quad*8];
        #pragma unroll
        for (int nt=0;nt<16;++nt){
          int bidx = (nt>>2)*68 + (nt&3)*16 + l16 + kx*DIL;
          f16x8 bf = *(const f16x8*)&Bl[bidx*32 + ((quad ^ ((bidx>>1)&3))<<3)];
          acc[nt] = MFMA16(af, bf, acc[nt]);
        }
      }
      __syncthreads();
    }
  }

  int cob = co0 + wave*16 + quad*4;
  float bs[4];
  #pragma unroll
  for (int r=0;r<4;++r) bs[r] = bias[cob+r];

  if (MODE==0){
    // resid staged coalesced f32 into LDS (exact), two 32-channel halves
    const float* rb = resid + ((size_t)(b*256 + co0) << 12) + y0*64;
    #pragma unroll
    for (int half=0; half<2; ++half){
      #pragma unroll
      for (int p=0;p<8;++p){
        int i = p*256 + tid;
        int c32 = i>>6, px0 = (i&63)*4;
        float4 u = *(const float4*)(rb + (((size_t)(half*32 + c32))<<12) + px0);
        *(float4*)&cs4[c32*256 + (px0 ^ (((c32>>2)&3)<<3))] = u;
      }
      __syncthreads();
      if ((wave>>1) == half){
        #pragma unroll
        for (int nt=0;nt<16;++nt){
          int y = y0 + (nt>>2), x = (nt&3)*16 + l16;
          int px = (nt>>2)*64 + (nt&3)*16 + l16;
          #pragma unroll
          for (int r=0;r<4;++r){
            int co = cob + r;
            int c32 = ((wave&1)<<4) + (quad<<2) + r;
            float rv = cs4[c32*256 + (px ^ (((c32>>2)&3)<<3))];
            float v = lrelu(acc[nt][r] + bs[r]) + rv;
            size_t o = (size_t)(b*256+co)*4096 + y*64 + x;
            outf[o] = v;
            outh[((size_t)((b*64+y)*64+x)<<8) + co] = (f16)v;
          }
        }
      }
      __syncthreads();
    }
  } else {
    #pragma unroll
    for (int nt=0;nt<16;++nt){
      int y = y0 + (nt>>2), x = (nt&3)*16 + l16;
      #pragma unroll
      for (int r=0;r<4;++r){
        int co = cob + r;
        float v = acc[nt][r] + bs[r];
        size_t o = (size_t)(b*256+co)*4096 + y*64 + x;
        outf[o] = v;
      }
    }
  }
}

// ======================= instance-norm stats (NCHW f32) =======================
__global__ __launch_bounds__(256) void k_instats(const float* __restrict__ v, float2* __restrict__ st)
{
  int bc = blockIdx.x;
  const float* p = v + (size_t)bc*4096;
  int tid = threadIdx.x;
  float s=0.f, ss=0.f;
  #pragma unroll
  for (int it=0; it<4; ++it){
    float4 u = *(const float4*)(p + it*1024 + tid*4);
    s  += u.x+u.y+u.z+u.w;
    ss += u.x*u.x + u.y*u.y + u.z*u.z + u.w*u.w;
  }
  #pragma unroll
  for (int off=32; off; off>>=1){ s += __shfl_down(s, off, 64); ss += __shfl_down(ss, off, 64); }
  __shared__ float rs[4], rss[4];
  int wave = tid>>6, lane = tid&63;
  if (lane==0){ rs[wave]=s; rss[wave]=ss; }
  __syncthreads();
  if (tid==0){
    float S = rs[0]+rs[1]+rs[2]+rs[3], SS = rss[0]+rss[1]+rss[2]+rss[3];
    float mu = S*(1.f/4096.f);
    float var = SS*(1.f/4096.f) - mu*mu;
    st[bc] = make_float2(mu, rsqrtf(var + 1e-5f));
  }
}

// final: out += lrelu(IN(c2))
__global__ __launch_bounds__(256) void k_final(float* __restrict__ out, const float* __restrict__ c2,
                                               const float2* __restrict__ st)
{
  int i4 = blockIdx.x*256 + threadIdx.x;
  float2 s = st[i4>>10];
  float4 u = *(const float4*)(c2 + (size_t)i4*4);
  float4 o = *(const float4*)(out + (size_t)i4*4);
  o.x += lrelu((u.x - s.x)*s.y);
  o.y += lrelu((u.y - s.x)*s.y);
  o.z += lrelu((u.z - s.x)*s.y);
  o.w += lrelu((u.w - s.x)*s.y);
  *(float4*)(out + (size_t)i4*4) = o;
}

// ======================= launch =======================
extern "C" void kernel_launch(void* const* d_in, const int* in_sizes, int n_in,
                              void* d_out, int out_size, void* d_ws, size_t ws_size,
                              hipStream_t stream)
{
  const float* x    = (const float*)d_in[0];
  const float* mask = (const float*)d_in[1];
  const float* dis  = (const float*)d_in[2];
  const float* lapa = (const float*)d_in[3];
  const float* Wq   = (const float*)d_in[4];
  const float* bq   = (const float*)d_in[5];
  const float* Wk   = (const float*)d_in[6];
  const float* bk   = (const float*)d_in[7];
  const float* Wv   = (const float*)d_in[8];
  const float* bv   = (const float*)d_in[9];
  const float* nq   = (const float*)d_in[10];
  const float* nk   = (const float*)d_in[11];
  const float* nv   = (const float*)d_in[12];
  const float* Wo   = (const float*)d_in[13];
  const float* bo   = (const float*)d_in[14];
  const float* W1   = (const float*)d_in[15];
  const float* b1   = (const float*)d_in[16];
  const float* W2   = (const float*)d_in[17];
  const float* b2   = (const float*)d_in[18];

  char* w = (char*)d_ws;
  f16*   xh    = (f16*)(w + 0);
  f16*   Qp    = (f16*)(w + 33554432);
  f16*   Kp    = (f16*)(w + 67108864);
  f16*   Vt    = (f16*)(w + 100663296);
  f16*   attnb = (f16*)(w + 134217728);
  f16*   outbf = (f16*)(w + 0);
  float* c1    = (float*)(w + 33554432);
  f16*   y1    = (f16*)(w + 100663296);
  float* c2    = (float*)(w + 33554432);
  f16*   wqh   = (f16*)(w + 167772160);
  f16*   wkh   = wqh + 65536;
  f16*   wvh   = wkh + 65536;
  f16*   wt0   = (f16*)(w + 168165376);
  f16*   wt1   = wt0 + 589824;
  f16*   wt2   = wt1 + 589824;
  float* pmk   = (float*)(w + 171704320);
  float2* st1  = (float2*)(w + 171720704);
  float2* st2  = (float2*)(w + 171753472);
  float* out   = (float*)d_out;

  k_prep1x1<<<768, 256, 0, stream>>>(Wq, Wk, Wv, wqh, wkh, wvh);
  k_prep3x3<<<6912, 256, 0, stream>>>(Wo, W1, W2, wt0, wt1, wt2);
  k_pmask<<<16, 256, 0, stream>>>(mask, pmk);
  k_nchw2nhwc<<<1024, 256, 0, stream>>>(x, nullptr, xh);
  k_qkv<<<3072, 256, 0, stream>>>(xh, wqh, wkh, wvh, bq, bk, bv, nq, nk, nv, Qp, Kp, Vt);
  k_attn<<<1024, 256, 0, stream>>>(Qp, Kp, Vt, dis, lapa, pmk, attnb);
  k_conv3<1,0><<<1024, 256, 0, stream>>>(attnb, wt0, bo, x, out, outbf);
  k_conv3<2,1><<<1024, 256, 0, stream>>>(outbf, wt1, b1, nullptr, c1, nullptr);
  k_instats<<<4096, 256, 0, stream>>>(c1, st1);
  k_nchw2nhwc<<<1024, 256, 0, stream>>>(c1, st1, y1);
  k_conv3<1,1><<<1024, 256, 0, stream>>>(y1, wt2, b2, nullptr, c2, nullptr);
  k_instats<<<4096, 256, 0, stream>>>(c2, st2);
  k_final<<<16384, 256, 0, stream>>>(out, c2, st2);
}

// Round 6
// 923.744 us; speedup vs baseline: 1.6422x; 1.0431x over previous
//
#include <hip/hip_runtime.h>
#include <cstdint>
#include <cstddef>

typedef _Float16 f16;
typedef _Float16 f16x8 __attribute__((ext_vector_type(8)));
typedef _Float16 f16x4 __attribute__((ext_vector_type(4)));
typedef float    f32x4 __attribute__((ext_vector_type(4)));

#define MFMA16(a,b,c) __builtin_amdgcn_mfma_f32_16x16x32_f16((a),(b),(c),0,0,0)

__device__ __forceinline__ float lrelu(float v){ return v >= 0.f ? v : 0.2f*v; }

// async global->LDS 16B copy; global addr per-lane, LDS dest = wave base + lane*16
__device__ __forceinline__ void async_copy16(const f16* g, f16* l){
  __builtin_amdgcn_global_load_lds(
      (const __attribute__((address_space(1))) void*)(uintptr_t)(const void*)g,
      (__attribute__((address_space(3))) void*)(uint32_t)(uintptr_t)(void*)l,
      16, 0, 0);
}

// ======================= prep kernels =======================

__global__ __launch_bounds__(256) void k_prep1x1(
    const float* __restrict__ wq, const float* __restrict__ wk, const float* __restrict__ wv,
    f16* __restrict__ oq, f16* __restrict__ ok, f16* __restrict__ ov)
{
  int i = blockIdx.x*256 + threadIdx.x;
  int sel = i >> 16, r = i & 65535;
  const float* s = sel==0 ? wq : (sel==1 ? wk : wv);
  f16* d = sel==0 ? oq : (sel==1 ? ok : ov);
  d[r] = (f16)s[r];
}

// 3x3 conv weights (co,ci,3,3) fp32 -> fp16 layout [tap][co][ci]
__global__ __launch_bounds__(256) void k_prep3x3(
    const float* __restrict__ w0, const float* __restrict__ w1, const float* __restrict__ w2,
    f16* __restrict__ o0, f16* __restrict__ o1, f16* __restrict__ o2)
{
  int i = blockIdx.x*256 + threadIdx.x;
  int sel = i / 589824;
  int r = i - sel*589824;
  int t = r >> 16; int rr = r & 65535; int co = rr >> 8; int ci = rr & 255;
  const float* s = sel==0 ? w0 : (sel==1 ? w1 : w2);
  f16* d = sel==0 ? o0 : (sel==1 ? o1 : o2);
  d[r] = (f16)s[(co*256 + ci)*9 + t];
}

__global__ __launch_bounds__(256) void k_pmask(const float* __restrict__ mask, float* __restrict__ pm)
{
  int t = blockIdx.x*256 + threadIdx.x;
  int b = t >> 8, n = t & 255;
  int y0 = (n>>4)<<2, x0 = (n&15)<<2;
  const float* mb = mask + b*4096;
  float s = 0.f;
  #pragma unroll
  for (int i=0;i<4;++i)
    #pragma unroll
    for (int j=0;j<4;++j) s += mb[(y0+i)*64 + x0+j];
  pm[t] = (s*(1.f/16.f) < 0.5f) ? 1.f : 0.f;
}

// ======================= NCHW f32 -> NHWC f16 (optional IN+lrelu) ===========
__global__ __launch_bounds__(256) void k_nchw2nhwc(
    const float* __restrict__ src, const float2* __restrict__ st, f16* __restrict__ dst)
{
  int idx = blockIdx.x;
  int y = idx & 63, b = idx >> 6;
  int tid = threadIdx.x;
  __shared__ f16 T[64*264];

  {
    const float* row = src + (size_t)(b*256+tid)*4096 + y*64;
    float mu = 0.f, ri = 1.f;
    bool doin = (st != nullptr);
    if (doin){ float2 s = st[b*256+tid]; mu = s.x; ri = s.y; }
    #pragma unroll
    for (int j=0;j<16;++j){
      float4 u = *(const float4*)(row + j*4);
      int x = j*4;
      float a0=(u.x-mu)*ri, a1=(u.y-mu)*ri, a2=(u.z-mu)*ri, a3=(u.w-mu)*ri;
      if (doin){ a0=lrelu(a0); a1=lrelu(a1); a2=lrelu(a2); a3=lrelu(a3); }
      T[(x+0)*264+tid]=(f16)a0; T[(x+1)*264+tid]=(f16)a1;
      T[(x+2)*264+tid]=(f16)a2; T[(x+3)*264+tid]=(f16)a3;
    }
  }
  __syncthreads();
  {
    int oct = tid & 31, pxl = tid >> 5;
    #pragma unroll
    for (int p=0;p<8;++p){
      int px = p*8 + pxl;
      *(uint4*)&dst[((size_t)((b*64+y)*64+px)<<8) + oct*8] = *(const uint4*)&T[px*264 + oct*8];
    }
  }
}

// ======================= QKV 1x1-conv GEMM (NHWC input) =======================
__global__ __launch_bounds__(256, 4) void k_qkv(
    const f16* __restrict__ xh,
    const f16* __restrict__ wq, const f16* __restrict__ wk, const f16* __restrict__ wv,
    const float* __restrict__ bq, const float* __restrict__ bk, const float* __restrict__ bv,
    const float* __restrict__ nq, const float* __restrict__ nk, const float* __restrict__ nv,
    f16* __restrict__ Qp, f16* __restrict__ Kp, f16* __restrict__ Vt)
{
  int idx = blockIdx.x;
  int yt  = idx & 15; idx >>= 4;
  int cot = idx & 3;  idx >>= 2;
  int b   = idx & 15; idx >>= 4;
  int sel = idx;
  int tid = threadIdx.x;
  int wave = tid>>6, lane = tid&63, quad = lane>>4, l16 = lane&15;
  int co0 = cot*64, y0 = yt*4;

  const f16*  W    = sel==0 ? wq : (sel==1 ? wk : wv);
  const float* bias= sel==0 ? bq : (sel==1 ? bk : bv);
  const float* nz  = sel==0 ? nq : (sel==1 ? nk : nv);

  __shared__ f16 smem[20480];

  f32x4 acc[16];
  #pragma unroll
  for (int i=0;i<16;++i){ acc[i][0]=0.f; acc[i][1]=0.f; acc[i][2]=0.f; acc[i][3]=0.f; }

  int g8 = (((lane&3) ^ ((lane>>3)&3)) << 3);
  const f16* Wrow = W + ((co0 + wave*16 + (lane>>2))<<8) + g8;
  const f16* Xrow = xh + (((size_t)((b*64 + y0)*64))<<8) + g8;

  auto stage = [&](int buf, int kc){
    int ci0 = kc<<5;
    f16* Ab = smem + buf*2048;
    f16* Bb = smem + 4096 + buf*8192;
    async_copy16(Wrow + ci0, Ab + wave*512);
    #pragma unroll
    for (int j=0;j<4;++j){
      int px = j*64 + wave*16 + (lane>>2);
      async_copy16(Xrow + ((size_t)px<<8) + ci0, Bb + (j*64 + wave*16)*32);
    }
  };

  stage(0, 0);
  #pragma unroll
  for (int kc=0; kc<8; ++kc){
    int cur = kc & 1;
    if (kc < 7){
      stage(cur^1, kc+1);
      asm volatile("s_waitcnt vmcnt(5)\n\ts_barrier" ::: "memory");
    } else {
      asm volatile("s_waitcnt vmcnt(0)\n\ts_barrier" ::: "memory");
    }
    const f16* Al = smem + cur*2048;
    const f16* Bl = smem + 4096 + cur*8192;
    f16x8 af = *(const f16x8*)&Al[(wave*16+l16)*32 + ((quad ^ ((l16>>1)&3))<<3)];
    #pragma unroll
    for (int nt=0;nt<16;++nt){
      int bidx = (nt>>2)*64 + (nt&3)*16 + l16;
      f16x8 bf = *(const f16x8*)&Bl[bidx*32 + ((quad ^ ((bidx>>1)&3))<<3)];
      acc[nt] = MFMA16(af, bf, acc[nt]);
    }
    asm volatile("s_waitcnt lgkmcnt(0)\n\ts_barrier" ::: "memory");
  }

  // ---- epilogue ----
  int cob = co0 + wave*16 + quad*4;
  int h0 = cot*4, pr = yt;
  float bs[4];
  #pragma unroll
  for (int r=0;r<4;++r) bs[r] = bias[cob+r];

  const float* nzb = nz + ((size_t)(b*256 + co0) << 12) + y0*64;

  #pragma unroll
  for (int half=0; half<2; ++half){
    #pragma unroll
    for (int p=0;p<8;++p){
      int i = p*256 + tid;
      int c32 = i>>6, px0 = (i&63)*4;
      float4 u = *(const float4*)(nzb + (((size_t)(half*32 + c32))<<12) + px0);
      f16x4 h4; h4[0]=(f16)u.x; h4[1]=(f16)u.y; h4[2]=(f16)u.z; h4[3]=(f16)u.w;
      *(f16x4*)&smem[c32*256 + (px0 ^ (((c32>>2)&3)<<4))] = h4;
    }
    __syncthreads();
    if ((wave>>1) == half){
      #pragma unroll
      for (int nt=0;nt<16;++nt){
        int px = (nt>>2)*64 + (nt&3)*16 + l16;
        int n_ = (nt&3)*4 + (l16>>2);
        int ddb = (quad<<6) + ((nt>>2)<<2) + (l16&3);
        #pragma unroll
        for (int r=0;r<4;++r){
          int c32 = ((wave&1)<<4) + (quad<<2) + r;
          float nzv = (float)smem[c32*256 + (px ^ (((c32>>2)&3)<<4))];
          float v = acc[nt][r] + bs[r] + nzv;
          int dd = ddb + (r<<4);
          if (sel < 2){
            int row = ((wave&1)<<4) + n_;
            smem[8192 + row*280 + dd + ((dd>>6)<<3)] = (f16)v;
          } else {
            smem[8192 + ((wave&1)*4128) + dd*16 + ((dd>>6)<<3) + n_] = (f16)v;
          }
        }
      }
    }
    __syncthreads();
    if (sel < 2){
      f16* dst = sel==0 ? Qp : Kp;
      #pragma unroll
      for (int pass=0; pass<4; ++pass){
        int rowi = pass*8 + (tid>>5);
        int ch  = tid & 31;
        uint4 v = *(const uint4*)&smem[8192 + rowi*280 + ch*8 + ((ch>>3)<<3)];
        int grow = half*32 + rowi;
        *(uint4*)&dst[((b*16 + h0 + (grow>>4))<<16) + ((pr*16 + (grow&15))<<8) + ch*8] = v;
      }
    } else {
      #pragma unroll
      for (int p=0;p<4;++p){
        int i = p*256 + tid;
        int rw = i>>1, hf = i&1;
        int dd = rw & 255;
        uint4 v = *(const uint4*)&smem[8192 + (rw>>8)*4128 + dd*16 + ((dd>>6)<<3) + hf*8];
        *(uint4*)&Vt[((b*16 + h0 + half*2 + (rw>>8))<<16) + (dd<<8) + pr*16 + hf*8] = v;
      }
    }
    __syncthreads();
  }
}

// ======================= attention =======================
__global__ __launch_bounds__(256) void k_attn(
    const f16* __restrict__ Qp, const f16* __restrict__ Kp, const f16* __restrict__ Vt,
    const float* __restrict__ dis, const float* __restrict__ lap_a,
    const float* __restrict__ pm, f16* __restrict__ attn)
{
  int idx = blockIdx.x;
  int nt = idx & 3; idx >>= 2;
  int h  = idx & 15; idx >>= 4;
  int b  = idx;
  int tid = threadIdx.x, wave = tid>>6, lane = tid&63, quad = lane>>4, l16 = lane&15;
  int n0 = nt*64;
  int bh = (b*16 + h) << 16;

  __shared__ f16 smem[25344];
  f16* Ql  = smem;
  f16* KVl = smem + 16896;

  {
    int row = tid>>2, part = (tid&3)*64;
    const uint4* s = (const uint4*)&Qp[bh + ((n0+row)<<8) + part];
    uint4* d = (uint4*)&Ql[row*264 + part];
    #pragma unroll
    for (int j=0;j<8;++j) d[j] = s[j];
  }

  float splus = log1pf(expf(lap_a[0]));

  f32x4 sacc[16];
  #pragma unroll
  for (int i=0;i<16;++i){ sacc[i][0]=0.f; sacc[i][1]=0.f; sacc[i][2]=0.f; sacc[i][3]=0.f; }

  #pragma unroll
  for (int mc=0; mc<8; ++mc){
    __syncthreads();
    {
      int row = tid>>3, part = (tid&7)*32;
      const uint4* s = (const uint4*)&Kp[bh + ((mc*32+row)<<8) + part];
      uint4* d = (uint4*)&KVl[row*264 + part];
      #pragma unroll
      for (int j=0;j<4;++j) d[j] = s[j];
    }
    __syncthreads();
    #pragma unroll
    for (int kk=0;kk<8;++kk){
      f16x8 af = *(const f16x8*)&Ql[(wave*16+l16)*264 + kk*32 + quad*8];
      #pragma unroll
      for (int j=0;j<2;++j){
        f16x8 bf = *(const f16x8*)&KVl[(j*16+l16)*264 + kk*32 + quad*8];
        sacc[mc*2+j] = MFMA16(af, bf, sacc[mc*2+j]);
      }
    }
  }

  int nrow_base = wave*16 + quad*4;
  float pmv[16];
  #pragma unroll
  for (int t=0;t<16;++t) pmv[t] = pm[b*256 + t*16 + l16];

  #pragma unroll
  for (int r=0;r<4;++r){
    int n = n0 + nrow_base + r;
    float sv[16];
    float mx = -1e30f;
    #pragma unroll
    for (int t=0;t<16;++t){
      float s = sacc[t][r];
      s = (s + splus * dis[n*256 + t*16 + l16]) * 0.0625f;
      s = (pmv[t] > 0.5f) ? -1e30f : s;
      sv[t] = s;
      mx = fmaxf(mx, s);
    }
    #pragma unroll
    for (int off=1; off<16; off<<=1) mx = fmaxf(mx, __shfl_xor(mx, off, 64));
    float sum = 0.f;
    #pragma unroll
    for (int t=0;t<16;++t){ float e = __expf(sv[t]-mx); sv[t]=e; sum += e; }
    #pragma unroll
    for (int off=1; off<16; off<<=1) sum += __shfl_xor(sum, off, 64);
    float inv = 1.f/sum;
    #pragma unroll
    for (int t=0;t<16;++t) Ql[(nrow_base + r)*264 + t*16 + l16] = (f16)(sv[t]*inv);
  }

  f32x4 oacc[16];
  #pragma unroll
  for (int i=0;i<16;++i){ oacc[i][0]=0.f; oacc[i][1]=0.f; oacc[i][2]=0.f; oacc[i][3]=0.f; }

  for (int dc=0; dc<8; ++dc){
    __syncthreads();
    {
      int row = tid>>3, part = (tid&7)*32;
      const uint4* s = (const uint4*)&Vt[bh + ((dc*32+row)<<8) + part];
      uint4* d = (uint4*)&KVl[row*264 + part];
      #pragma unroll
      for (int j=0;j<4;++j) d[j] = s[j];
    }
    __syncthreads();
    #pragma unroll
    for (int kk=0;kk<8;++kk){
      f16x8 af = *(const f16x8*)&Ql[(wave*16+l16)*264 + kk*32 + quad*8];
      #pragma unroll
      for (int j=0;j<2;++j){
        f16x8 bf = *(const f16x8*)&KVl[(j*16+l16)*264 + kk*32 + quad*8];
        oacc[dc*2+j] = MFMA16(af, bf, oacc[dc*2+j]);
      }
    }
  }

  __syncthreads();
  #pragma unroll
  for (int dc=0; dc<8; ++dc){
    #pragma unroll
    for (int j=0;j<2;++j){
      int dd = dc*32 + j*16 + l16;
      int c_ = dd>>4;
      int pi = (dd>>2)&3, pj = dd&3;
      #pragma unroll
      for (int r=0;r<4;++r){
        int nl = nrow_base + r;
        int y_ = ((nl>>4)<<2) + pi;
        int x  = ((nl&15)<<2) + pj;
        smem[(y_*64 + x)*24 + c_] = (f16)oacc[dc*2+j][r];
      }
    }
  }
  __syncthreads();
  #pragma unroll
  for (int p=0;p<4;++p){
    int pix = p*256 + tid;
    int y_ = pix>>6, x = pix&63;
    uint4 v0 = *(const uint4*)&smem[pix*24];
    uint4 v1 = *(const uint4*)&smem[pix*24 + 8];
    size_t o = ((size_t)((b*64 + nt*16 + y_)*64 + x)<<8) + h*16;
    *(uint4*)&attn[o]     = v0;
    *(uint4*)&attn[o + 8] = v1;
  }
}

// ======================= 3x3 conv (implicit GEMM, NHWC input) ================
// 4x4 fragment blocking: wave = one y-row x 64 px, all 64 co.
// Per kx: 4 af + 4 bf ds_reads feed 16 MFMAs (2.1x less LDS-read traffic).
// Staging: double-buffered regs, loads for t+1 issued before ds_write/MFMA of t.
template<int DIL, int MODE>
__global__ __launch_bounds__(256) void k_conv3(
    const f16* __restrict__ in, const f16* __restrict__ Wt, const float* __restrict__ bias,
    const float* __restrict__ resid, float* __restrict__ outf, f16* __restrict__ outh)
{
  int idx = blockIdx.x;
  int yt  = idx & 15; idx >>= 4;
  int cot = idx & 3;  idx >>= 2;
  int b   = idx;
  int y0 = yt*4, co0 = cot*64;
  int tid = threadIdx.x;
  int wave = tid>>6, lane = tid&63, quad = lane>>4, l16 = lane&15;

  // 32768B shared: K-loop Al [0,7680) f16, Bl [7680,16384) f16.
  // MODE0 epilogue: resid f32 [32c][256px] swizzled (two halves).
  __shared__ float cs4[8192];
  f16* Al = (f16*)cs4;
  f16* Bl = (f16*)cs4 + 7680;

  f32x4 acc[4][4];   // [xi][cq]
  #pragma unroll
  for (int xi=0;xi<4;++xi)
    #pragma unroll
    for (int cq=0;cq<4;++cq){ acc[xi][cq][0]=0.f; acc[xi][cq][1]=0.f; acc[xi][cq][2]=0.f; acc[xi][cq][3]=0.f; }

  constexpr int PXR = 64 + 2*DIL;
  constexpr int NU4 = 16*PXR;

  int aco = tid>>2, ap = (tid&3)*8;

  auto load_regs = [&](int t, uint4* rA, uint4* rB){
    int ky = t>>3, kc = t&7, ci0 = kc*32;
    int yb = y0 + DIL*(ky-1);
    #pragma unroll
    for (int kx=0;kx<3;++kx)
      rA[kx] = *(const uint4*)&Wt[((ky*3+kx)<<16) + ((co0+aco)<<8) + ci0 + ap];
    #pragma unroll
    for (int p=0;p<5;++p){
      int i = p*256 + tid;
      uint4 v = make_uint4(0u,0u,0u,0u);
      if (i < NU4){
        int px = i>>2, oct = i&3;
        int yr = px / PXR, xp = px - yr*PXR;
        int yy = yb + yr, xx = xp - DIL;
        if (yy>=0 && yy<64 && xx>=0 && xx<64)
          v = *(const uint4*)&in[((size_t)((b*64+yy)*64+xx)<<8) + ci0 + oct*8];
      }
      rB[p] = v;
    }
  };

  auto store_lds = [&](const uint4* rA, const uint4* rB){
    #pragma unroll
    for (int kx=0;kx<3;++kx)
      *(uint4*)&Al[kx*2560 + aco*40 + ap] = rA[kx];
    #pragma unroll
    for (int p=0;p<5;++p){
      int i = p*256 + tid;
      if (i < NU4){
        int px = i>>2, oct = i&3;
        int yr = px / PXR, xp = px - yr*PXR;
        int si = yr*68 + xp;
        *(uint4*)&Bl[si*32 + ((oct ^ ((si>>1)&3))<<3)] = rB[p];
      }
    }
  };

  auto mfma_phase = [&](){
    #pragma unroll
    for (int kx=0;kx<3;++kx){
      f16x8 af[4], bfv[4];
      #pragma unroll
      for (int cq=0;cq<4;++cq)
        af[cq] = *(const f16x8*)&Al[kx*2560 + (cq*16+l16)*40 + quad*8];
      #pragma unroll
      for (int xi=0;xi<4;++xi){
        int bidx = wave*68 + xi*16 + l16 + kx*DIL;
        bfv[xi] = *(const f16x8*)&Bl[bidx*32 + ((quad ^ ((bidx>>1)&3))<<3)];
      }
      #pragma unroll
      for (int xi=0;xi<4;++xi)
        #pragma unroll
        for (int cq=0;cq<4;++cq)
          acc[xi][cq] = MFMA16(af[cq], bfv[xi], acc[xi][cq]);
    }
  };

  uint4 rA0[3], rB0[5], rA1[3], rB1[5];
  load_regs(0, rA0, rB0);
  for (int t=0; t<24; t+=2){
    __syncthreads();
    if (t+1 < 24) load_regs(t+1, rA1, rB1);
    store_lds(rA0, rB0);
    __syncthreads();
    mfma_phase();

    __syncthreads();
    if (t+2 < 24) load_regs(t+2, rA0, rB0);
    store_lds(rA1, rB1);
    __syncthreads();
    mfma_phase();
  }
  __syncthreads();

  int y = y0 + wave;
  float bsv[4][4];
  #pragma unroll
  for (int cq=0;cq<4;++cq)
    #pragma unroll
    for (int r=0;r<4;++r) bsv[cq][r] = bias[co0 + cq*16 + quad*4 + r];

  if (MODE==0){
    // resid staged coalesced f32 into LDS (exact), two 32-channel halves
    const float* rb = resid + ((size_t)(b*256 + co0) << 12) + y0*64;
    #pragma unroll
    for (int half=0; half<2; ++half){
      #pragma unroll
      for (int p=0;p<8;++p){
        int i = p*256 + tid;
        int c32 = i>>6, px0 = (i&63)*4;
        float4 u = *(const float4*)(rb + (((size_t)(half*32 + c32))<<12) + px0);
        *(float4*)&cs4[c32*256 + (px0 ^ (((c32>>2)&3)<<3))] = u;
      }
      __syncthreads();
      #pragma unroll
      for (int cq2=0; cq2<2; ++cq2){
        int cq = half*2 + cq2;
        #pragma unroll
        for (int xi=0; xi<4; ++xi){
          int x = xi*16 + l16;
          int px = wave*64 + xi*16 + l16;
          #pragma unroll
          for (int r=0;r<4;++r){
            int co = co0 + cq*16 + quad*4 + r;
            int c32 = cq2*16 + quad*4 + r;
            float rv = cs4[c32*256 + (px ^ (((c32>>2)&3)<<3))];
            float v = lrelu(acc[xi][cq][r] + bsv[cq][r]) + rv;
            size_t o = (size_t)(b*256+co)*4096 + y*64 + x;
            outf[o] = v;
            outh[((size_t)((b*64+y)*64+x)<<8) + co] = (f16)v;
          }
        }
      }
      __syncthreads();
    }
  } else {
    #pragma unroll
    for (int xi=0; xi<4; ++xi){
      int x = xi*16 + l16;
      #pragma unroll
      for (int cq=0;cq<4;++cq){
        #pragma unroll
        for (int r=0;r<4;++r){
          int co = co0 + cq*16 + quad*4 + r;
          float v = acc[xi][cq][r] + bsv[cq][r];
          size_t o = (size_t)(b*256+co)*4096 + y*64 + x;
          outf[o] = v;
        }
      }
    }
  }
}

// ======================= instance-norm stats (NCHW f32) =======================
__global__ __launch_bounds__(256) void k_instats(const float* __restrict__ v, float2* __restrict__ st)
{
  int bc = blockIdx.x;
  const float* p = v + (size_t)bc*4096;
  int tid = threadIdx.x;
  float s=0.f, ss=0.f;
  #pragma unroll
  for (int it=0; it<4; ++it){
    float4 u = *(const float4*)(p + it*1024 + tid*4);
    s  += u.x+u.y+u.z+u.w;
    ss += u.x*u.x + u.y*u.y + u.z*u.z + u.w*u.w;
  }
  #pragma unroll
  for (int off=32; off; off>>=1){ s += __shfl_down(s, off, 64); ss += __shfl_down(ss, off, 64); }
  __shared__ float rs[4], rss[4];
  int wave = tid>>6, lane = tid&63;
  if (lane==0){ rs[wave]=s; rss[wave]=ss; }
  __syncthreads();
  if (tid==0){
    float S = rs[0]+rs[1]+rs[2]+rs[3], SS = rss[0]+rss[1]+rss[2]+rss[3];
    float mu = S*(1.f/4096.f);
    float var = SS*(1.f/4096.f) - mu*mu;
    st[bc] = make_float2(mu, rsqrtf(var + 1e-5f));
  }
}

// final: out += lrelu(IN(c2))
__global__ __launch_bounds__(256) void k_final(float* __restrict__ out, const float* __restrict__ c2,
                                               const float2* __restrict__ st)
{
  int i4 = blockIdx.x*256 + threadIdx.x;
  float2 s = st[i4>>10];
  float4 u = *(const float4*)(c2 + (size_t)i4*4);
  float4 o = *(const float4*)(out + (size_t)i4*4);
  o.x += lrelu((u.x - s.x)*s.y);
  o.y += lrelu((u.y - s.x)*s.y);
  o.z += lrelu((u.z - s.x)*s.y);
  o.w += lrelu((u.w - s.x)*s.y);
  *(float4*)(out + (size_t)i4*4) = o;
}

// ======================= launch =======================
extern "C" void kernel_launch(void* const* d_in, const int* in_sizes, int n_in,
                              void* d_out, int out_size, void* d_ws, size_t ws_size,
                              hipStream_t stream)
{
  const float* x    = (const float*)d_in[0];
  const float* mask = (const float*)d_in[1];
  const float* dis  = (const float*)d_in[2];
  const float* lapa = (const float*)d_in[3];
  const float* Wq   = (const float*)d_in[4];
  const float* bq   = (const float*)d_in[5];
  const float* Wk   = (const float*)d_in[6];
  const float* bk   = (const float*)d_in[7];
  const float* Wv   = (const float*)d_in[8];
  const float* bv   = (const float*)d_in[9];
  const float* nq   = (const float*)d_in[10];
  const float* nk   = (const float*)d_in[11];
  const float* nv   = (const float*)d_in[12];
  const float* Wo   = (const float*)d_in[13];
  const float* bo   = (const float*)d_in[14];
  const float* W1   = (const float*)d_in[15];
  const float* b1   = (const float*)d_in[16];
  const float* W2   = (const float*)d_in[17];
  const float* b2   = (const float*)d_in[18];

  char* w = (char*)d_ws;
  f16*   xh    = (f16*)(w + 0);
  f16*   Qp    = (f16*)(w + 33554432);
  f16*   Kp    = (f16*)(w + 67108864);
  f16*   Vt    = (f16*)(w + 100663296);
  f16*   attnb = (f16*)(w + 134217728);
  f16*   outbf = (f16*)(w + 0);
  float* c1    = (float*)(w + 33554432);
  f16*   y1    = (f16*)(w + 100663296);
  float* c2    = (float*)(w + 33554432);
  f16*   wqh   = (f16*)(w + 167772160);
  f16*   wkh   = wqh + 65536;
  f16*   wvh   = wkh + 65536;
  f16*   wt0   = (f16*)(w + 168165376);
  f16*   wt1   = wt0 + 589824;
  f16*   wt2   = wt1 + 589824;
  float* pmk   = (float*)(w + 171704320);
  float2* st1  = (float2*)(w + 171720704);
  float2* st2  = (float2*)(w + 171753472);
  float* out   = (float*)d_out;

  k_prep1x1<<<768, 256, 0, stream>>>(Wq, Wk, Wv, wqh, wkh, wvh);
  k_prep3x3<<<6912, 256, 0, stream>>>(Wo, W1, W2, wt0, wt1, wt2);
  k_pmask<<<16, 256, 0, stream>>>(mask, pmk);
  k_nchw2nhwc<<<1024, 256, 0, stream>>>(x, nullptr, xh);
  k_qkv<<<3072, 256, 0, stream>>>(xh, wqh, wkh, wvh, bq, bk, bv, nq, nk, nv, Qp, Kp, Vt);
  k_attn<<<1024, 256, 0, stream>>>(Qp, Kp, Vt, dis, lapa, pmk, attnb);
  k_conv3<1,0><<<1024, 256, 0, stream>>>(attnb, wt0, bo, x, out, outbf);
  k_conv3<2,1><<<1024, 256, 0, stream>>>(outbf, wt1, b1, nullptr, c1, nullptr);
  k_instats<<<4096, 256, 0, stream>>>(c1, st1);
  k_nchw2nhwc<<<1024, 256, 0, stream>>>(c1, st1, y1);
  k_conv3<1,1><<<1024, 256, 0, stream>>>(y1, wt2, b2, nullptr, c2, nullptr);
  k_instats<<<4096, 256, 0, stream>>>(c2, st2);
  k_final<<<16384, 256, 0, stream>>>(out, c2, st2);
}

// Round 7
// 873.975 us; speedup vs baseline: 1.7357x; 1.0569x over previous
//
#include <hip/hip_runtime.h>
#include <cstdint>
#include <cstddef>

typedef _Float16 f16;
typedef _Float16 f16x8 __attribute__((ext_vector_type(8)));
typedef _Float16 f16x4 __attribute__((ext_vector_type(4)));
typedef float    f32x4 __attribute__((ext_vector_type(4)));

#define MFMA16(a,b,c) __builtin_amdgcn_mfma_f32_16x16x32_f16((a),(b),(c),0,0,0)

__device__ __forceinline__ float lrelu(float v){ return v >= 0.f ? v : 0.2f*v; }

// async global->LDS 16B copy; global addr per-lane, LDS dest = wave base + lane*16
__device__ __forceinline__ void async_copy16(const f16* g, f16* l){
  __builtin_amdgcn_global_load_lds(
      (const __attribute__((address_space(1))) void*)(uintptr_t)(const void*)g,
      (__attribute__((address_space(3))) void*)(uint32_t)(uintptr_t)(void*)l,
      16, 0, 0);
}

// ======================= prep kernels =======================

__global__ __launch_bounds__(256) void k_prep1x1(
    const float* __restrict__ wq, const float* __restrict__ wk, const float* __restrict__ wv,
    f16* __restrict__ oq, f16* __restrict__ ok, f16* __restrict__ ov)
{
  int i = blockIdx.x*256 + threadIdx.x;
  int sel = i >> 16, r = i & 65535;
  const float* s = sel==0 ? wq : (sel==1 ? wk : wv);
  f16* d = sel==0 ? oq : (sel==1 ? ok : ov);
  d[r] = (f16)s[r];
}

// 3x3 conv weights (co,ci,3,3) fp32 -> fp16 layout [tap][co][ci]
__global__ __launch_bounds__(256) void k_prep3x3(
    const float* __restrict__ w0, const float* __restrict__ w1, const float* __restrict__ w2,
    f16* __restrict__ o0, f16* __restrict__ o1, f16* __restrict__ o2)
{
  int i = blockIdx.x*256 + threadIdx.x;
  int sel = i / 589824;
  int r = i - sel*589824;
  int t = r >> 16; int rr = r & 65535; int co = rr >> 8; int ci = rr & 255;
  const float* s = sel==0 ? w0 : (sel==1 ? w1 : w2);
  f16* d = sel==0 ? o0 : (sel==1 ? o1 : o2);
  d[r] = (f16)s[(co*256 + ci)*9 + t];
}

__global__ __launch_bounds__(256) void k_pmask(const float* __restrict__ mask, float* __restrict__ pm)
{
  int t = blockIdx.x*256 + threadIdx.x;
  int b = t >> 8, n = t & 255;
  int y0 = (n>>4)<<2, x0 = (n&15)<<2;
  const float* mb = mask + b*4096;
  float s = 0.f;
  #pragma unroll
  for (int i=0;i<4;++i)
    #pragma unroll
    for (int j=0;j<4;++j) s += mb[(y0+i)*64 + x0+j];
  pm[t] = (s*(1.f/16.f) < 0.5f) ? 1.f : 0.f;
}

// ======================= NCHW f32 -> NHWC f16 (optional IN+lrelu) ===========
__global__ __launch_bounds__(256) void k_nchw2nhwc(
    const float* __restrict__ src, const float2* __restrict__ st, f16* __restrict__ dst)
{
  int idx = blockIdx.x;
  int y = idx & 63, b = idx >> 6;
  int tid = threadIdx.x;
  __shared__ f16 T[64*264];

  {
    const float* row = src + (size_t)(b*256+tid)*4096 + y*64;
    float mu = 0.f, ri = 1.f;
    bool doin = (st != nullptr);
    if (doin){ float2 s = st[b*256+tid]; mu = s.x; ri = s.y; }
    #pragma unroll
    for (int j=0;j<16;++j){
      float4 u = *(const float4*)(row + j*4);
      int x = j*4;
      float a0=(u.x-mu)*ri, a1=(u.y-mu)*ri, a2=(u.z-mu)*ri, a3=(u.w-mu)*ri;
      if (doin){ a0=lrelu(a0); a1=lrelu(a1); a2=lrelu(a2); a3=lrelu(a3); }
      T[(x+0)*264+tid]=(f16)a0; T[(x+1)*264+tid]=(f16)a1;
      T[(x+2)*264+tid]=(f16)a2; T[(x+3)*264+tid]=(f16)a3;
    }
  }
  __syncthreads();
  {
    int oct = tid & 31, pxl = tid >> 5;
    #pragma unroll
    for (int p=0;p<8;++p){
      int px = p*8 + pxl;
      *(uint4*)&dst[((size_t)((b*64+y)*64+px)<<8) + oct*8] = *(const uint4*)&T[px*264 + oct*8];
    }
  }
}

// ======================= QKV 1x1-conv GEMM (NHWC input) =======================
__global__ __launch_bounds__(256, 4) void k_qkv(
    const f16* __restrict__ xh,
    const f16* __restrict__ wq, const f16* __restrict__ wk, const f16* __restrict__ wv,
    const float* __restrict__ bq, const float* __restrict__ bk, const float* __restrict__ bv,
    const float* __restrict__ nq, const float* __restrict__ nk, const float* __restrict__ nv,
    f16* __restrict__ Qp, f16* __restrict__ Kp, f16* __restrict__ Vt)
{
  int idx = blockIdx.x;
  int yt  = idx & 15; idx >>= 4;
  int cot = idx & 3;  idx >>= 2;
  int b   = idx & 15; idx >>= 4;
  int sel = idx;
  int tid = threadIdx.x;
  int wave = tid>>6, lane = tid&63, quad = lane>>4, l16 = lane&15;
  int co0 = cot*64, y0 = yt*4;

  const f16*  W    = sel==0 ? wq : (sel==1 ? wk : wv);
  const float* bias= sel==0 ? bq : (sel==1 ? bk : bv);
  const float* nz  = sel==0 ? nq : (sel==1 ? nk : nv);

  __shared__ f16 smem[20480];

  f32x4 acc[16];
  #pragma unroll
  for (int i=0;i<16;++i){ acc[i][0]=0.f; acc[i][1]=0.f; acc[i][2]=0.f; acc[i][3]=0.f; }

  int g8 = (((lane&3) ^ ((lane>>3)&3)) << 3);
  const f16* Wrow = W + ((co0 + wave*16 + (lane>>2))<<8) + g8;
  const f16* Xrow = xh + (((size_t)((b*64 + y0)*64))<<8) + g8;

  auto stage = [&](int buf, int kc){
    int ci0 = kc<<5;
    f16* Ab = smem + buf*2048;
    f16* Bb = smem + 4096 + buf*8192;
    async_copy16(Wrow + ci0, Ab + wave*512);
    #pragma unroll
    for (int j=0;j<4;++j){
      int px = j*64 + wave*16 + (lane>>2);
      async_copy16(Xrow + ((size_t)px<<8) + ci0, Bb + (j*64 + wave*16)*32);
    }
  };

  stage(0, 0);
  #pragma unroll
  for (int kc=0; kc<8; ++kc){
    int cur = kc & 1;
    if (kc < 7){
      stage(cur^1, kc+1);
      asm volatile("s_waitcnt vmcnt(5)\n\ts_barrier" ::: "memory");
    } else {
      asm volatile("s_waitcnt vmcnt(0)\n\ts_barrier" ::: "memory");
    }
    const f16* Al = smem + cur*2048;
    const f16* Bl = smem + 4096 + cur*8192;
    f16x8 af = *(const f16x8*)&Al[(wave*16+l16)*32 + ((quad ^ ((l16>>1)&3))<<3)];
    #pragma unroll
    for (int nt=0;nt<16;++nt){
      int bidx = (nt>>2)*64 + (nt&3)*16 + l16;
      f16x8 bf = *(const f16x8*)&Bl[bidx*32 + ((quad ^ ((bidx>>1)&3))<<3)];
      acc[nt] = MFMA16(af, bf, acc[nt]);
    }
    asm volatile("s_waitcnt lgkmcnt(0)\n\ts_barrier" ::: "memory");
  }

  // ---- epilogue ----
  int cob = co0 + wave*16 + quad*4;
  int h0 = cot*4, pr = yt;
  float bs[4];
  #pragma unroll
  for (int r=0;r<4;++r) bs[r] = bias[cob+r];

  const float* nzb = nz + ((size_t)(b*256 + co0) << 12) + y0*64;

  #pragma unroll
  for (int half=0; half<2; ++half){
    #pragma unroll
    for (int p=0;p<8;++p){
      int i = p*256 + tid;
      int c32 = i>>6, px0 = (i&63)*4;
      float4 u = *(const float4*)(nzb + (((size_t)(half*32 + c32))<<12) + px0);
      f16x4 h4; h4[0]=(f16)u.x; h4[1]=(f16)u.y; h4[2]=(f16)u.z; h4[3]=(f16)u.w;
      *(f16x4*)&smem[c32*256 + (px0 ^ (((c32>>2)&3)<<4))] = h4;
    }
    __syncthreads();
    if ((wave>>1) == half){
      #pragma unroll
      for (int nt=0;nt<16;++nt){
        int px = (nt>>2)*64 + (nt&3)*16 + l16;
        int n_ = (nt&3)*4 + (l16>>2);
        int ddb = (quad<<6) + ((nt>>2)<<2) + (l16&3);
        #pragma unroll
        for (int r=0;r<4;++r){
          int c32 = ((wave&1)<<4) + (quad<<2) + r;
          float nzv = (float)smem[c32*256 + (px ^ (((c32>>2)&3)<<4))];
          float v = acc[nt][r] + bs[r] + nzv;
          int dd = ddb + (r<<4);
          if (sel < 2){
            int row = ((wave&1)<<4) + n_;
            smem[8192 + row*280 + dd + ((dd>>6)<<3)] = (f16)v;
          } else {
            smem[8192 + ((wave&1)*4128) + dd*16 + ((dd>>6)<<3) + n_] = (f16)v;
          }
        }
      }
    }
    __syncthreads();
    if (sel < 2){
      f16* dst = sel==0 ? Qp : Kp;
      #pragma unroll
      for (int pass=0; pass<4; ++pass){
        int rowi = pass*8 + (tid>>5);
        int ch  = tid & 31;
        uint4 v = *(const uint4*)&smem[8192 + rowi*280 + ch*8 + ((ch>>3)<<3)];
        int grow = half*32 + rowi;
        *(uint4*)&dst[((b*16 + h0 + (grow>>4))<<16) + ((pr*16 + (grow&15))<<8) + ch*8] = v;
      }
    } else {
      #pragma unroll
      for (int p=0;p<4;++p){
        int i = p*256 + tid;
        int rw = i>>1, hf = i&1;
        int dd = rw & 255;
        uint4 v = *(const uint4*)&smem[8192 + (rw>>8)*4128 + dd*16 + ((dd>>6)<<3) + hf*8];
        *(uint4*)&Vt[((b*16 + h0 + half*2 + (rw>>8))<<16) + (dd<<8) + pr*16 + hf*8] = v;
      }
    }
    __syncthreads();
  }
}

// ======================= attention =======================
__global__ __launch_bounds__(256) void k_attn(
    const f16* __restrict__ Qp, const f16* __restrict__ Kp, const f16* __restrict__ Vt,
    const float* __restrict__ dis, const float* __restrict__ lap_a,
    const float* __restrict__ pm, f16* __restrict__ attn)
{
  int idx = blockIdx.x;
  int nt = idx & 3; idx >>= 2;
  int h  = idx & 15; idx >>= 4;
  int b  = idx;
  int tid = threadIdx.x, wave = tid>>6, lane = tid&63, quad = lane>>4, l16 = lane&15;
  int n0 = nt*64;
  int bh = (b*16 + h) << 16;

  __shared__ f16 smem[25344];
  f16* Ql  = smem;
  f16* KVl = smem + 16896;

  {
    int row = tid>>2, part = (tid&3)*64;
    const uint4* s = (const uint4*)&Qp[bh + ((n0+row)<<8) + part];
    uint4* d = (uint4*)&Ql[row*264 + part];
    #pragma unroll
    for (int j=0;j<8;++j) d[j] = s[j];
  }

  float splus = log1pf(expf(lap_a[0]));

  f32x4 sacc[16];
  #pragma unroll
  for (int i=0;i<16;++i){ sacc[i][0]=0.f; sacc[i][1]=0.f; sacc[i][2]=0.f; sacc[i][3]=0.f; }

  #pragma unroll
  for (int mc=0; mc<8; ++mc){
    __syncthreads();
    {
      int row = tid>>3, part = (tid&7)*32;
      const uint4* s = (const uint4*)&Kp[bh + ((mc*32+row)<<8) + part];
      uint4* d = (uint4*)&KVl[row*264 + part];
      #pragma unroll
      for (int j=0;j<4;++j) d[j] = s[j];
    }
    __syncthreads();
    #pragma unroll
    for (int kk=0;kk<8;++kk){
      f16x8 af = *(const f16x8*)&Ql[(wave*16+l16)*264 + kk*32 + quad*8];
      #pragma unroll
      for (int j=0;j<2;++j){
        f16x8 bf = *(const f16x8*)&KVl[(j*16+l16)*264 + kk*32 + quad*8];
        sacc[mc*2+j] = MFMA16(af, bf, sacc[mc*2+j]);
      }
    }
  }

  int nrow_base = wave*16 + quad*4;
  float pmv[16];
  #pragma unroll
  for (int t=0;t<16;++t) pmv[t] = pm[b*256 + t*16 + l16];

  #pragma unroll
  for (int r=0;r<4;++r){
    int n = n0 + nrow_base + r;
    float sv[16];
    float mx = -1e30f;
    #pragma unroll
    for (int t=0;t<16;++t){
      float s = sacc[t][r];
      s = (s + splus * dis[n*256 + t*16 + l16]) * 0.0625f;
      s = (pmv[t] > 0.5f) ? -1e30f : s;
      sv[t] = s;
      mx = fmaxf(mx, s);
    }
    #pragma unroll
    for (int off=1; off<16; off<<=1) mx = fmaxf(mx, __shfl_xor(mx, off, 64));
    float sum = 0.f;
    #pragma unroll
    for (int t=0;t<16;++t){ float e = __expf(sv[t]-mx); sv[t]=e; sum += e; }
    #pragma unroll
    for (int off=1; off<16; off<<=1) sum += __shfl_xor(sum, off, 64);
    float inv = 1.f/sum;
    #pragma unroll
    for (int t=0;t<16;++t) Ql[(nrow_base + r)*264 + t*16 + l16] = (f16)(sv[t]*inv);
  }

  f32x4 oacc[16];
  #pragma unroll
  for (int i=0;i<16;++i){ oacc[i][0]=0.f; oacc[i][1]=0.f; oacc[i][2]=0.f; oacc[i][3]=0.f; }

  for (int dc=0; dc<8; ++dc){
    __syncthreads();
    {
      int row = tid>>3, part = (tid&7)*32;
      const uint4* s = (const uint4*)&Vt[bh + ((dc*32+row)<<8) + part];
      uint4* d = (uint4*)&KVl[row*264 + part];
      #pragma unroll
      for (int j=0;j<4;++j) d[j] = s[j];
    }
    __syncthreads();
    #pragma unroll
    for (int kk=0;kk<8;++kk){
      f16x8 af = *(const f16x8*)&Ql[(wave*16+l16)*264 + kk*32 + quad*8];
      #pragma unroll
      for (int j=0;j<2;++j){
        f16x8 bf = *(const f16x8*)&KVl[(j*16+l16)*264 + kk*32 + quad*8];
        oacc[dc*2+j] = MFMA16(af, bf, oacc[dc*2+j]);
      }
    }
  }

  __syncthreads();
  #pragma unroll
  for (int dc=0; dc<8; ++dc){
    #pragma unroll
    for (int j=0;j<2;++j){
      int dd = dc*32 + j*16 + l16;
      int c_ = dd>>4;
      int pi = (dd>>2)&3, pj = dd&3;
      #pragma unroll
      for (int r=0;r<4;++r){
        int nl = nrow_base + r;
        int y_ = ((nl>>4)<<2) + pi;
        int x  = ((nl&15)<<2) + pj;
        smem[(y_*64 + x)*24 + c_] = (f16)oacc[dc*2+j][r];
      }
    }
  }
  __syncthreads();
  #pragma unroll
  for (int p=0;p<4;++p){
    int pix = p*256 + tid;
    int y_ = pix>>6, x = pix&63;
    uint4 v0 = *(const uint4*)&smem[pix*24];
    uint4 v1 = *(const uint4*)&smem[pix*24 + 8];
    size_t o = ((size_t)((b*64 + nt*16 + y_)*64 + x)<<8) + h*16;
    *(uint4*)&attn[o]     = v0;
    *(uint4*)&attn[o + 8] = v1;
  }
}

// ======================= 3x3 conv (implicit GEMM, NHWC input) ================
// 4x4 fragment blocking (wave = one y-row x 64 px, all 64 co): per kx,
// 4 af + 4 bf ds_reads feed 16 MFMAs (24 b128 reads/iter/wave vs 51).
// Staging: serial (transient regs -> ds_write), NO register double-buffer
// (Round-6 dbuf spilled to scratch: WRITE 102->287MB).
template<int DIL, int MODE>
__global__ __launch_bounds__(256) void k_conv3(
    const f16* __restrict__ in, const f16* __restrict__ Wt, const float* __restrict__ bias,
    const float* __restrict__ resid, float* __restrict__ outf, f16* __restrict__ outh)
{
  int idx = blockIdx.x;
  int yt  = idx & 15; idx >>= 4;
  int cot = idx & 3;  idx >>= 2;
  int b   = idx;
  int y0 = yt*4, co0 = cot*64;
  int tid = threadIdx.x;
  int wave = tid>>6, lane = tid&63, quad = lane>>4, l16 = lane&15;

  // 32768B shared: K-loop Al [0,7680) f16, Bl [7680,16384) f16.
  // MODE0 epilogue: resid f32 [32c][256px] swizzled (two halves).
  __shared__ float cs4[8192];
  f16* Al = (f16*)cs4;
  f16* Bl = (f16*)cs4 + 7680;

  f32x4 acc[4][4];   // [xi][cq]
  #pragma unroll
  for (int xi=0;xi<4;++xi)
    #pragma unroll
    for (int cq=0;cq<4;++cq){ acc[xi][cq][0]=0.f; acc[xi][cq][1]=0.f; acc[xi][cq][2]=0.f; acc[xi][cq][3]=0.f; }

  constexpr int PXR = 64 + 2*DIL;
  constexpr int NU4 = 16*PXR;

  int aco = tid>>2, ap = (tid&3)*8;

  for (int ky=0; ky<3; ++ky){
    int yb = y0 + DIL*(ky-1);
    for (int kc=0; kc<8; ++kc){
      int ci0 = kc*32;
      {
        #pragma unroll
        for (int kx=0;kx<3;++kx)
          *(uint4*)&Al[kx*2560 + aco*40 + ap] =
              *(const uint4*)&Wt[((ky*3+kx)<<16) + ((co0+aco)<<8) + ci0 + ap];
      }
      #pragma unroll
      for (int p=0;p<5;++p){
        int i = p*256 + tid;
        if (i < NU4){
          int px = i>>2, oct = i&3;
          int yr = px / PXR, xp = px - yr*PXR;
          int yy = yb + yr, xx = xp - DIL;
          uint4 v = make_uint4(0u,0u,0u,0u);
          if (yy>=0 && yy<64 && xx>=0 && xx<64)
            v = *(const uint4*)&in[((size_t)((b*64+yy)*64+xx)<<8) + ci0 + oct*8];
          int si = yr*68 + xp;
          *(uint4*)&Bl[si*32 + ((oct ^ ((si>>1)&3))<<3)] = v;
        }
      }
      __syncthreads();
      #pragma unroll
      for (int kx=0;kx<3;++kx){
        f16x8 af[4], bfv[4];
        #pragma unroll
        for (int cq=0;cq<4;++cq)
          af[cq] = *(const f16x8*)&Al[kx*2560 + (cq*16+l16)*40 + quad*8];
        #pragma unroll
        for (int xi=0;xi<4;++xi){
          int bidx = wave*68 + xi*16 + l16 + kx*DIL;
          bfv[xi] = *(const f16x8*)&Bl[bidx*32 + ((quad ^ ((bidx>>1)&3))<<3)];
        }
        #pragma unroll
        for (int xi=0;xi<4;++xi)
          #pragma unroll
          for (int cq=0;cq<4;++cq)
            acc[xi][cq] = MFMA16(af[cq], bfv[xi], acc[xi][cq]);
      }
      __syncthreads();
    }
  }

  int y = y0 + wave;
  float bsv[4][4];
  #pragma unroll
  for (int cq=0;cq<4;++cq)
    #pragma unroll
    for (int r=0;r<4;++r) bsv[cq][r] = bias[co0 + cq*16 + quad*4 + r];

  if (MODE==0){
    // resid staged coalesced f32 into LDS (exact), two 32-channel halves
    const float* rb = resid + ((size_t)(b*256 + co0) << 12) + y0*64;
    #pragma unroll
    for (int half=0; half<2; ++half){
      #pragma unroll
      for (int p=0;p<8;++p){
        int i = p*256 + tid;
        int c32 = i>>6, px0 = (i&63)*4;
        float4 u = *(const float4*)(rb + (((size_t)(half*32 + c32))<<12) + px0);
        *(float4*)&cs4[c32*256 + (px0 ^ (((c32>>2)&3)<<3))] = u;
      }
      __syncthreads();
      #pragma unroll
      for (int cq2=0; cq2<2; ++cq2){
        int cq = half*2 + cq2;
        #pragma unroll
        for (int xi=0; xi<4; ++xi){
          int x = xi*16 + l16;
          int px = wave*64 + xi*16 + l16;
          #pragma unroll
          for (int r=0;r<4;++r){
            int co = co0 + cq*16 + quad*4 + r;
            int c32 = cq2*16 + quad*4 + r;
            float rv = cs4[c32*256 + (px ^ (((c32>>2)&3)<<3))];
            float v = lrelu(acc[xi][cq][r] + bsv[cq][r]) + rv;
            size_t o = (size_t)(b*256+co)*4096 + y*64 + x;
            outf[o] = v;
            outh[((size_t)((b*64+y)*64+x)<<8) + co] = (f16)v;
          }
        }
      }
      __syncthreads();
    }
  } else {
    #pragma unroll
    for (int xi=0; xi<4; ++xi){
      int x = xi*16 + l16;
      #pragma unroll
      for (int cq=0;cq<4;++cq){
        #pragma unroll
        for (int r=0;r<4;++r){
          int co = co0 + cq*16 + quad*4 + r;
          float v = acc[xi][cq][r] + bsv[cq][r];
          size_t o = (size_t)(b*256+co)*4096 + y*64 + x;
          outf[o] = v;
        }
      }
    }
  }
}

// ======================= instance-norm stats (NCHW f32) =======================
__global__ __launch_bounds__(256) void k_instats(const float* __restrict__ v, float2* __restrict__ st)
{
  int bc = blockIdx.x;
  const float* p = v + (size_t)bc*4096;
  int tid = threadIdx.x;
  float s=0.f, ss=0.f;
  #pragma unroll
  for (int it=0; it<4; ++it){
    float4 u = *(const float4*)(p + it*1024 + tid*4);
    s  += u.x+u.y+u.z+u.w;
    ss += u.x*u.x + u.y*u.y + u.z*u.z + u.w*u.w;
  }
  #pragma unroll
  for (int off=32; off; off>>=1){ s += __shfl_down(s, off, 64); ss += __shfl_down(ss, off, 64); }
  __shared__ float rs[4], rss[4];
  int wave = tid>>6, lane = tid&63;
  if (lane==0){ rs[wave]=s; rss[wave]=ss; }
  __syncthreads();
  if (tid==0){
    float S = rs[0]+rs[1]+rs[2]+rs[3], SS = rss[0]+rss[1]+rss[2]+rss[3];
    float mu = S*(1.f/4096.f);
    float var = SS*(1.f/4096.f) - mu*mu;
    st[bc] = make_float2(mu, rsqrtf(var + 1e-5f));
  }
}

// final: out += lrelu(IN(c2))
__global__ __launch_bounds__(256) void k_final(float* __restrict__ out, const float* __restrict__ c2,
                                               const float2* __restrict__ st)
{
  int i4 = blockIdx.x*256 + threadIdx.x;
  float2 s = st[i4>>10];
  float4 u = *(const float4*)(c2 + (size_t)i4*4);
  float4 o = *(const float4*)(out + (size_t)i4*4);
  o.x += lrelu((u.x - s.x)*s.y);
  o.y += lrelu((u.y - s.x)*s.y);
  o.z += lrelu((u.z - s.x)*s.y);
  o.w += lrelu((u.w - s.x)*s.y);
  *(float4*)(out + (size_t)i4*4) = o;
}

// ======================= launch =======================
extern "C" void kernel_launch(void* const* d_in, const int* in_sizes, int n_in,
                              void* d_out, int out_size, void* d_ws, size_t ws_size,
                              hipStream_t stream)
{
  const float* x    = (const float*)d_in[0];
  const float* mask = (const float*)d_in[1];
  const float* dis  = (const float*)d_in[2];
  const float* lapa = (const float*)d_in[3];
  const float* Wq   = (const float*)d_in[4];
  const float* bq   = (const float*)d_in[5];
  const float* Wk   = (const float*)d_in[6];
  const float* bk   = (const float*)d_in[7];
  const float* Wv   = (const float*)d_in[8];
  const float* bv   = (const float*)d_in[9];
  const float* nq   = (const float*)d_in[10];
  const float* nk   = (const float*)d_in[11];
  const float* nv   = (const float*)d_in[12];
  const float* Wo   = (const float*)d_in[13];
  const float* bo   = (const float*)d_in[14];
  const float* W1   = (const float*)d_in[15];
  const float* b1   = (const float*)d_in[16];
  const float* W2   = (const float*)d_in[17];
  const float* b2   = (const float*)d_in[18];

  char* w = (char*)d_ws;
  f16*   xh    = (f16*)(w + 0);
  f16*   Qp    = (f16*)(w + 33554432);
  f16*   Kp    = (f16*)(w + 67108864);
  f16*   Vt    = (f16*)(w + 100663296);
  f16*   attnb = (f16*)(w + 134217728);
  f16*   outbf = (f16*)(w + 0);
  float* c1    = (float*)(w + 33554432);
  f16*   y1    = (f16*)(w + 100663296);
  float* c2    = (float*)(w + 33554432);
  f16*   wqh   = (f16*)(w + 167772160);
  f16*   wkh   = wqh + 65536;
  f16*   wvh   = wkh + 65536;
  f16*   wt0   = (f16*)(w + 168165376);
  f16*   wt1   = wt0 + 589824;
  f16*   wt2   = wt1 + 589824;
  float* pmk   = (float*)(w + 171704320);
  float2* st1  = (float2*)(w + 171720704);
  float2* st2  = (float2*)(w + 171753472);
  float* out   = (float*)d_out;

  k_prep1x1<<<768, 256, 0, stream>>>(Wq, Wk, Wv, wqh, wkh, wvh);
  k_prep3x3<<<6912, 256, 0, stream>>>(Wo, W1, W2, wt0, wt1, wt2);
  k_pmask<<<16, 256, 0, stream>>>(mask, pmk);
  k_nchw2nhwc<<<1024, 256, 0, stream>>>(x, nullptr, xh);
  k_qkv<<<3072, 256, 0, stream>>>(xh, wqh, wkh, wvh, bq, bk, bv, nq, nk, nv, Qp, Kp, Vt);
  k_attn<<<1024, 256, 0, stream>>>(Qp, Kp, Vt, dis, lapa, pmk, attnb);
  k_conv3<1,0><<<1024, 256, 0, stream>>>(attnb, wt0, bo, x, out, outbf);
  k_conv3<2,1><<<1024, 256, 0, stream>>>(outbf, wt1, b1, nullptr, c1, nullptr);
  k_instats<<<4096, 256, 0, stream>>>(c1, st1);
  k_nchw2nhwc<<<1024, 256, 0, stream>>>(c1, st1, y1);
  k_conv3<1,1><<<1024, 256, 0, stream>>>(y1, wt2, b2, nullptr, c2, nullptr);
  k_instats<<<4096, 256, 0, stream>>>(c2, st2);
  k_final<<<16384, 256, 0, stream>>>(out, c2, st2);
}